// Round 8
// baseline (374.540 us; speedup 1.0000x reference)
//
#include <hip/hip_runtime.h>
#include <hip/hip_bf16.h>

#define N_NODES 100000
#define N_EDGES 1600000
#define D 64
#define BN_EPS 1e-5f
#define NB_SCAN 391  // ceil(N_NODES/256)
#define AGS 68       // agg LDS row stride (floats): 272B, 16B-aligned, 2-way banks (free)
#define XRS 68       // root LDS row stride (shorts): 136B, 8B-aligned uint2 ops, 2-way banks

// ---------------- CSR build (round-6 proven) ----------------

__global__ __launch_bounds__(256) void k_hist_rank(const int* __restrict__ ei,
                                                   int* __restrict__ deg,
                                                   int* __restrict__ tmp) {
  int e = (blockIdx.x * 256 + threadIdx.x) * 4;
  if (e >= N_EDGES) return;
  int4 s = *(const int4*)(ei + e);
  int4 d = *(const int4*)(ei + N_EDGES + e);
  int4 t;
  t.x = s.x | (atomicAdd(&deg[d.x], 1) << 17);
  t.y = s.y | (atomicAdd(&deg[d.y], 1) << 17);
  t.z = s.z | (atomicAdd(&deg[d.z], 1) << 17);
  t.w = s.w | (atomicAdd(&deg[d.w], 1) << 17);
  *(int4*)(tmp + e) = t;
}

__global__ __launch_bounds__(256) void k_offsets(const int* __restrict__ deg,
                                                 int* __restrict__ cursor,
                                                 int* __restrict__ gcount) {
  __shared__ int sd[256];
  __shared__ int sbase;
  int tid = threadIdx.x;
  int i = blockIdx.x * 256 + tid;
  int v = (i < N_NODES) ? deg[i] : 0;
  sd[tid] = v;
  __syncthreads();
  for (int ofs = 1; ofs < 256; ofs <<= 1) {
    int t = (tid >= ofs) ? sd[tid - ofs] : 0;
    __syncthreads();
    sd[tid] += t;
    __syncthreads();
  }
  if (tid == 255) sbase = atomicAdd(gcount, sd[255]);
  __syncthreads();
  if (i < N_NODES) cursor[i] = sbase + sd[tid] - v;  // exclusive segment start
}

__global__ __launch_bounds__(256) void k_scatter_rank(const int* __restrict__ ei,
                                                      const int* __restrict__ tmp,
                                                      const int* __restrict__ cursor,
                                                      int* __restrict__ ssrc) {
  int e = (blockIdx.x * 256 + threadIdx.x) * 4;
  if (e >= N_EDGES) return;
  int4 d = *(const int4*)(ei + N_EDGES + e);
  int4 t = *(const int4*)(tmp + e);
  ssrc[cursor[d.x] + ((unsigned)t.x >> 17)] = t.x & 0x1ffff;
  ssrc[cursor[d.y] + ((unsigned)t.y >> 17)] = t.y & 0x1ffff;
  ssrc[cursor[d.z] + ((unsigned)t.z >> 17)] = t.z & 0x1ffff;
  ssrc[cursor[d.w] + ((unsigned)t.w >> 17)] = t.w & 0x1ffff;
}

// ---------------- helpers ----------------

static __device__ inline unsigned short f2bf_bits(float v) {
  __hip_bfloat16 h = __float2bfloat16(v);
  return *reinterpret_cast<unsigned short*>(&h);
}

// add 8 bf16 (one uint4 = 16B) into f32 accumulators
static __device__ inline void add_bf8(float* a, uint4 v) {
  unsigned int b;
  b = v.x << 16;         a[0] += *(float*)&b;
  b = v.x & 0xffff0000u; a[1] += *(float*)&b;
  b = v.y << 16;         a[2] += *(float*)&b;
  b = v.y & 0xffff0000u; a[3] += *(float*)&b;
  b = v.z << 16;         a[4] += *(float*)&b;
  b = v.z & 0xffff0000u; a[5] += *(float*)&b;
  b = v.w << 16;         a[6] += *(float*)&b;
  b = v.w & 0xffff0000u; a[7] += *(float*)&b;
}

static __device__ inline void set_bf8(float* a, ushort4 u0, ushort4 u1) {
  unsigned int b;
  b = (unsigned int)u0.x << 16; a[0] = *(float*)&b;
  b = (unsigned int)u0.y << 16; a[1] = *(float*)&b;
  b = (unsigned int)u0.z << 16; a[2] = *(float*)&b;
  b = (unsigned int)u0.w << 16; a[3] = *(float*)&b;
  b = (unsigned int)u1.x << 16; a[4] = *(float*)&b;
  b = (unsigned int)u1.y << 16; a[5] = *(float*)&b;
  b = (unsigned int)u1.z << 16; a[6] = *(float*)&b;
  b = (unsigned int)u1.w << 16; a[7] = *(float*)&b;
}

// x f32 -> bf16 copy (into upper half of d_out; dead until layer 2 rewrites)
__global__ __launch_bounds__(256) void k_cvt(const float* __restrict__ x,
                                             unsigned short* __restrict__ xb) {
  long i = (long)(blockIdx.x * 256 + threadIdx.x) * 4;
  if (i >= (long)N_NODES * D) return;
  float4 v = *(const float4*)(x + i);
  ushort4 u;
  u.x = f2bf_bits(v.x); u.y = f2bf_bits(v.y);
  u.z = f2bf_bits(v.z); u.w = f2bf_bits(v.w);
  *(ushort4*)(xb + i) = u;
}

// ---------------- fused SAGE layer ----------------
// Phase 0: bitonic-sort the tile's 64 nodes by degree; snake-pair so each
// 8-lane group's two nodes sum to ~deg_min+deg_max (wave-balanced gather).
// Phase 1: gather-aggregate bf16 rows (uint4/lane, 8 in flight); stage agg
// (f32) + root row (bf16) in LDS. 26.4 KB -> 6 blocks/CU.
// Phase 2: SGPR weights, all row data from LDS (round-4 lesson).

template <bool OUT_BF16>
__global__ __launch_bounds__(256) void sage_fused(
    const int* __restrict__ cursor, const int* __restrict__ deg_a,
    const int* __restrict__ ssrc,
    const unsigned short* __restrict__ gsrc,  // bf16 rows [N][D]: gather + root
    const float* __restrict__ wl, const float* __restrict__ bl,
    const float* __restrict__ wr,
    const float* __restrict__ gamma, const float* __restrict__ beta,
    const float* __restrict__ mean, const float* __restrict__ var,
    void* __restrict__ out) {
  __shared__ float ag_t[64 * AGS];           // 17408 B
  __shared__ unsigned short xr_t[64 * XRS];  // 8704 B
  __shared__ int skey[64];                   // 256 B
  const int tid = threadIdx.x;
  const int base = blockIdx.x * 64;
  const int grp = tid >> 3;  // 8-lane group, 0..31
  const int q8 = tid & 7;    // 16B chunk = 8 bf16 features

  // phase 0: sort nodes by degree (key = deg<<8 | r, unique, deterministic)
  if (tid < 64) {
    int n = base + tid;
    int dv = (n < N_NODES) ? deg_a[n] : 0;
    skey[tid] = (dv << 8) | tid;
  }
  __syncthreads();
  for (int k2 = 2; k2 <= 64; k2 <<= 1) {
    for (int j = k2 >> 1; j > 0; j >>= 1) {
      if (tid < 64) {
        int ixj = tid ^ j;
        if (ixj > tid) {
          int a = skey[tid], b = skey[ixj];
          bool up = ((tid & k2) == 0);
          if (up ? (a > b) : (a < b)) { skey[tid] = b; skey[ixj] = a; }
        }
      }
      __syncthreads();
    }
  }

  // phase 1: two passes; snake ranks (grp, 63-grp)
  for (int p = 0; p < 2; ++p) {
    int rank = p == 0 ? grp : 63 - grp;
    int r = skey[rank] & 0xff;
    int n = base + r;
    if (n < N_NODES) {
      float a[8] = {0.f, 0.f, 0.f, 0.f, 0.f, 0.f, 0.f, 0.f};
      int st = cursor[n];
      int dg = deg_a[n];
      int u = 0;
      for (; u + 8 <= dg; u += 8) {
        int s0 = ssrc[st + u + 0], s1 = ssrc[st + u + 1];
        int s2 = ssrc[st + u + 2], s3 = ssrc[st + u + 3];
        int s4 = ssrc[st + u + 4], s5 = ssrc[st + u + 5];
        int s6 = ssrc[st + u + 6], s7 = ssrc[st + u + 7];
        uint4 v0 = *((const uint4*)(gsrc + (long)s0 * D) + q8);
        uint4 v1 = *((const uint4*)(gsrc + (long)s1 * D) + q8);
        uint4 v2 = *((const uint4*)(gsrc + (long)s2 * D) + q8);
        uint4 v3 = *((const uint4*)(gsrc + (long)s3 * D) + q8);
        uint4 v4 = *((const uint4*)(gsrc + (long)s4 * D) + q8);
        uint4 v5 = *((const uint4*)(gsrc + (long)s5 * D) + q8);
        uint4 v6 = *((const uint4*)(gsrc + (long)s6 * D) + q8);
        uint4 v7 = *((const uint4*)(gsrc + (long)s7 * D) + q8);
        add_bf8(a, v0); add_bf8(a, v1); add_bf8(a, v2); add_bf8(a, v3);
        add_bf8(a, v4); add_bf8(a, v5); add_bf8(a, v6); add_bf8(a, v7);
      }
      if (u + 4 <= dg) {
        int s0 = ssrc[st + u + 0], s1 = ssrc[st + u + 1];
        int s2 = ssrc[st + u + 2], s3 = ssrc[st + u + 3];
        uint4 v0 = *((const uint4*)(gsrc + (long)s0 * D) + q8);
        uint4 v1 = *((const uint4*)(gsrc + (long)s1 * D) + q8);
        uint4 v2 = *((const uint4*)(gsrc + (long)s2 * D) + q8);
        uint4 v3 = *((const uint4*)(gsrc + (long)s3 * D) + q8);
        add_bf8(a, v0); add_bf8(a, v1); add_bf8(a, v2); add_bf8(a, v3);
        u += 4;
      }
      for (; u < dg; ++u) {
        uint4 v = *((const uint4*)(gsrc + (long)ssrc[st + u] * D) + q8);
        add_bf8(a, v);
      }
      float invd = 1.0f / fmaxf((float)dg, 1.0f);
#pragma unroll
      for (int j = 0; j < 8; ++j) a[j] *= invd;
      uint4 rv = *((const uint4*)(gsrc + (long)n * D) + q8);  // root row (bf16)
      *(float4*)&ag_t[r * AGS + q8 * 8 + 0] = make_float4(a[0], a[1], a[2], a[3]);
      *(float4*)&ag_t[r * AGS + q8 * 8 + 4] = make_float4(a[4], a[5], a[6], a[7]);
      *(uint2*)&xr_t[r * XRS + q8 * 8 + 0] = make_uint2(rv.x, rv.y);
      *(uint2*)&xr_t[r * XRS + q8 * 8 + 4] = make_uint2(rv.z, rv.w);
    }
  }
  __syncthreads();

  // phase 2: thread = (node = tid&63, dim-block g = wave). SGPR weights.
  const int n = tid & 63;
  const int g = __builtin_amdgcn_readfirstlane(tid >> 6);  // 0..3
  const long gn = base + n;
  const float* arow = &ag_t[n * AGS];
  const unsigned short* xrow = &xr_t[n * XRS];

  for (int dt = 0; dt < 4; ++dt) {
    const int d0 = g * 16 + dt * 4;
    float a0 = bl[d0 + 0], a1 = bl[d0 + 1], a2 = bl[d0 + 2], a3 = bl[d0 + 3];
    const float* w0l = wl + (long)(d0 + 0) * 64;
    const float* w1l = wl + (long)(d0 + 1) * 64;
    const float* w2l = wl + (long)(d0 + 2) * 64;
    const float* w3l = wl + (long)(d0 + 3) * 64;
    const float* w0r = wr + (long)(d0 + 0) * 64;
    const float* w1r = wr + (long)(d0 + 1) * 64;
    const float* w2r = wr + (long)(d0 + 2) * 64;
    const float* w3r = wr + (long)(d0 + 3) * 64;
#pragma unroll
    for (int k = 0; k < 64; k += 8) {
      float4 i0 = *(const float4*)(arow + k);
      float4 i1 = *(const float4*)(arow + k + 4);
      ushort4 u0 = *(const ushort4*)(xrow + k);
      ushort4 u1 = *(const ushort4*)(xrow + k + 4);
      float jr[8];
      set_bf8(jr, u0, u1);
      a0 += i0.x * w0l[k] + i0.y * w0l[k + 1] + i0.z * w0l[k + 2] + i0.w * w0l[k + 3]
          + i1.x * w0l[k + 4] + i1.y * w0l[k + 5] + i1.z * w0l[k + 6] + i1.w * w0l[k + 7]
          + jr[0] * w0r[k] + jr[1] * w0r[k + 1] + jr[2] * w0r[k + 2] + jr[3] * w0r[k + 3]
          + jr[4] * w0r[k + 4] + jr[5] * w0r[k + 5] + jr[6] * w0r[k + 6] + jr[7] * w0r[k + 7];
      a1 += i0.x * w1l[k] + i0.y * w1l[k + 1] + i0.z * w1l[k + 2] + i0.w * w1l[k + 3]
          + i1.x * w1l[k + 4] + i1.y * w1l[k + 5] + i1.z * w1l[k + 6] + i1.w * w1l[k + 7]
          + jr[0] * w1r[k] + jr[1] * w1r[k + 1] + jr[2] * w1r[k + 2] + jr[3] * w1r[k + 3]
          + jr[4] * w1r[k + 4] + jr[5] * w1r[k + 5] + jr[6] * w1r[k + 6] + jr[7] * w1r[k + 7];
      a2 += i0.x * w2l[k] + i0.y * w2l[k + 1] + i0.z * w2l[k + 2] + i0.w * w2l[k + 3]
          + i1.x * w2l[k + 4] + i1.y * w2l[k + 5] + i1.z * w2l[k + 6] + i1.w * w2l[k + 7]
          + jr[0] * w2r[k] + jr[1] * w2r[k + 1] + jr[2] * w2r[k + 2] + jr[3] * w2r[k + 3]
          + jr[4] * w2r[k + 4] + jr[5] * w2r[k + 5] + jr[6] * w2r[k + 6] + jr[7] * w2r[k + 7];
      a3 += i0.x * w3l[k] + i0.y * w3l[k + 1] + i0.z * w3l[k + 2] + i0.w * w3l[k + 3]
          + i1.x * w3l[k + 4] + i1.y * w3l[k + 5] + i1.z * w3l[k + 6] + i1.w * w3l[k + 7]
          + jr[0] * w3r[k] + jr[1] * w3r[k + 1] + jr[2] * w3r[k + 2] + jr[3] * w3r[k + 3]
          + jr[4] * w3r[k + 4] + jr[5] * w3r[k + 5] + jr[6] * w3r[k + 6] + jr[7] * w3r[k + 7];
    }
    if (gn < N_NODES) {
      float sc0 = gamma[d0 + 0] * rsqrtf(var[d0 + 0] + BN_EPS);
      float sc1 = gamma[d0 + 1] * rsqrtf(var[d0 + 1] + BN_EPS);
      float sc2 = gamma[d0 + 2] * rsqrtf(var[d0 + 2] + BN_EPS);
      float sc3 = gamma[d0 + 3] * rsqrtf(var[d0 + 3] + BN_EPS);
      float sh0 = beta[d0 + 0] - mean[d0 + 0] * sc0;
      float sh1 = beta[d0 + 1] - mean[d0 + 1] * sc1;
      float sh2 = beta[d0 + 2] - mean[d0 + 2] * sc2;
      float sh3 = beta[d0 + 3] - mean[d0 + 3] * sc3;
      float o0 = a0 > 0.f ? a0 : expm1f(a0);
      float o1 = a1 > 0.f ? a1 : expm1f(a1);
      float o2 = a2 > 0.f ? a2 : expm1f(a2);
      float o3 = a3 > 0.f ? a3 : expm1f(a3);
      o0 = o0 * sc0 + sh0; o1 = o1 * sc1 + sh1;
      o2 = o2 * sc2 + sh2; o3 = o3 * sc3 + sh3;
      if constexpr (OUT_BF16) {
        ushort4 pk;
        pk.x = f2bf_bits(o0); pk.y = f2bf_bits(o1);
        pk.z = f2bf_bits(o2); pk.w = f2bf_bits(o3);
        *(ushort4*)((unsigned short*)out + gn * D + d0) = pk;
      } else {
        float4 f;
        f.x = o0; f.y = o1; f.z = o2; f.w = o3;
        *(float4*)((float*)out + gn * D + d0) = f;
      }
    }
  }
}

// ---------------- launch ----------------

extern "C" void kernel_launch(void* const* d_in, const int* in_sizes, int n_in,
                              void* d_out, int out_size, void* d_ws, size_t ws_size,
                              hipStream_t stream) {
  const float* x     = (const float*)d_in[0];
  const int*   ei    = (const int*)d_in[1];
  const float* w1_l  = (const float*)d_in[2];
  const float* b1_l  = (const float*)d_in[3];
  const float* w1_r  = (const float*)d_in[4];
  const float* w2_l  = (const float*)d_in[5];
  const float* b2_l  = (const float*)d_in[6];
  const float* w2_r  = (const float*)d_in[7];
  const float* bn1_g = (const float*)d_in[8];
  const float* bn1_b = (const float*)d_in[9];
  const float* bn1_m = (const float*)d_in[10];
  const float* bn1_v = (const float*)d_in[11];
  const float* bn2_g = (const float*)d_in[12];
  const float* bn2_b = (const float*)d_in[13];
  const float* bn2_m = (const float*)d_in[14];
  const float* bn2_v = (const float*)d_in[15];

  // ws layout (20.0 MB):
  int* deg    = (int*)d_ws;          // [N] (+pad, gcount at N)
  int* gcount = deg + N_NODES;       // [1]
  int* cursor = deg + 100008;        // [N] segment starts
  int* ssrc   = cursor + 100008;     // [E]
  unsigned short* h1 = (unsigned short*)(ssrc + N_EDGES);  // bf16 [N*D], 12.8 MB
  int* tmp    = (int*)h1;            // [E] rank|src, aliases h1 (dead until layer 1)

  // bf16 copy of x in the UPPER HALF of d_out (dead until layer 2 rewrites it)
  unsigned short* xb = (unsigned short*)d_out + (size_t)N_NODES * D;

  const int eb4 = (N_EDGES / 4 + 255) / 256;
  const int tiles = (N_NODES + 63) / 64;

  hipMemsetAsync(deg, 0, 100008 * sizeof(int), stream);  // deg + gcount
  k_hist_rank<<<eb4, 256, 0, stream>>>(ei, deg, tmp);
  k_offsets<<<NB_SCAN, 256, 0, stream>>>(deg, cursor, gcount);
  k_scatter_rank<<<eb4, 256, 0, stream>>>(ei, tmp, cursor, ssrc);
  k_cvt<<<(N_NODES * D / 4 + 255) / 256, 256, 0, stream>>>(x, xb);

  // layer 1: gather+root bf16 xb -> bf16 h1
  sage_fused<true><<<tiles, 256, 0, stream>>>(
      cursor, deg, ssrc, xb, w1_l, b1_l, w1_r,
      bn1_g, bn1_b, bn1_m, bn1_v, h1);
  // layer 2: gather+root bf16 h1 -> f32 d_out
  sage_fused<false><<<tiles, 256, 0, stream>>>(
      cursor, deg, ssrc, h1, w2_l, b2_l, w2_r,
      bn2_g, bn2_b, bn2_m, bn2_v, d_out);
}

// Round 9
// 352.858 us; speedup vs baseline: 1.0614x; 1.0614x over previous
//
#include <hip/hip_runtime.h>
#include <hip/hip_bf16.h>

#define N_NODES 100000
#define N_EDGES 1600000
#define D 64
#define BN_EPS 1e-5f
#define NB_SCAN 391  // ceil(N_NODES/256)
#define AGS 68       // agg LDS row stride (floats)
#define XRS 68       // root LDS row stride (shorts)

// ---------------- CSR build (round-6 proven) ----------------

__global__ __launch_bounds__(256) void k_hist_rank(const int* __restrict__ ei,
                                                   int* __restrict__ deg,
                                                   int* __restrict__ tmp) {
  int e = (blockIdx.x * 256 + threadIdx.x) * 4;
  if (e >= N_EDGES) return;
  int4 s = *(const int4*)(ei + e);
  int4 d = *(const int4*)(ei + N_EDGES + e);
  int4 t;
  t.x = s.x | (atomicAdd(&deg[d.x], 1) << 17);
  t.y = s.y | (atomicAdd(&deg[d.y], 1) << 17);
  t.z = s.z | (atomicAdd(&deg[d.z], 1) << 17);
  t.w = s.w | (atomicAdd(&deg[d.w], 1) << 17);
  *(int4*)(tmp + e) = t;
}

__global__ __launch_bounds__(256) void k_offsets(const int* __restrict__ deg,
                                                 int* __restrict__ cursor,
                                                 int* __restrict__ gcount) {
  __shared__ int sd[256];
  __shared__ int sbase;
  int tid = threadIdx.x;
  int i = blockIdx.x * 256 + tid;
  int v = (i < N_NODES) ? deg[i] : 0;
  sd[tid] = v;
  __syncthreads();
  for (int ofs = 1; ofs < 256; ofs <<= 1) {
    int t = (tid >= ofs) ? sd[tid - ofs] : 0;
    __syncthreads();
    sd[tid] += t;
    __syncthreads();
  }
  if (tid == 255) sbase = atomicAdd(gcount, sd[255]);
  __syncthreads();
  if (i < N_NODES) cursor[i] = sbase + sd[tid] - v;  // exclusive segment start
}

__global__ __launch_bounds__(256) void k_scatter_rank(const int* __restrict__ ei,
                                                      const int* __restrict__ tmp,
                                                      const int* __restrict__ cursor,
                                                      int* __restrict__ ssrc) {
  int e = (blockIdx.x * 256 + threadIdx.x) * 4;
  if (e >= N_EDGES) return;
  int4 d = *(const int4*)(ei + N_EDGES + e);
  int4 t = *(const int4*)(tmp + e);
  ssrc[cursor[d.x] + ((unsigned)t.x >> 17)] = t.x & 0x1ffff;
  ssrc[cursor[d.y] + ((unsigned)t.y >> 17)] = t.y & 0x1ffff;
  ssrc[cursor[d.z] + ((unsigned)t.z >> 17)] = t.z & 0x1ffff;
  ssrc[cursor[d.w] + ((unsigned)t.w >> 17)] = t.w & 0x1ffff;
}

// ---------------- helpers ----------------

static __device__ inline unsigned short f2bf_bits(float v) {
  __hip_bfloat16 h = __float2bfloat16(v);
  return *reinterpret_cast<unsigned short*>(&h);
}

// add 8 bf16 (one uint4 = 16B) into f32 accumulators
static __device__ inline void add_bf8(float* a, uint4 v) {
  unsigned int b;
  b = v.x << 16;         a[0] += *(float*)&b;
  b = v.x & 0xffff0000u; a[1] += *(float*)&b;
  b = v.y << 16;         a[2] += *(float*)&b;
  b = v.y & 0xffff0000u; a[3] += *(float*)&b;
  b = v.z << 16;         a[4] += *(float*)&b;
  b = v.z & 0xffff0000u; a[5] += *(float*)&b;
  b = v.w << 16;         a[6] += *(float*)&b;
  b = v.w & 0xffff0000u; a[7] += *(float*)&b;
}

static __device__ inline void set_bf8(float* a, ushort4 u0, ushort4 u1) {
  unsigned int b;
  b = (unsigned int)u0.x << 16; a[0] = *(float*)&b;
  b = (unsigned int)u0.y << 16; a[1] = *(float*)&b;
  b = (unsigned int)u0.z << 16; a[2] = *(float*)&b;
  b = (unsigned int)u0.w << 16; a[3] = *(float*)&b;
  b = (unsigned int)u1.x << 16; a[4] = *(float*)&b;
  b = (unsigned int)u1.y << 16; a[5] = *(float*)&b;
  b = (unsigned int)u1.z << 16; a[6] = *(float*)&b;
  b = (unsigned int)u1.w << 16; a[7] = *(float*)&b;
}

// x f32 -> bf16 copy (into upper half of d_out; dead until L2 gather rewrites)
__global__ __launch_bounds__(256) void k_cvt(const float* __restrict__ x,
                                             unsigned short* __restrict__ xb) {
  long i = (long)(blockIdx.x * 256 + threadIdx.x) * 4;
  if (i >= (long)N_NODES * D) return;
  float4 v = *(const float4*)(x + i);
  ushort4 u;
  u.x = f2bf_bits(v.x); u.y = f2bf_bits(v.y);
  u.z = f2bf_bits(v.z); u.w = f2bf_bits(v.w);
  *(ushort4*)(xb + i) = u;
}

// ---------------- pure gather kernel ----------------
// One 8-lane group per node; zero LDS; max concurrency. Reads bf16 rows,
// accumulates f32, writes agg row to global (bf16 for L1, f32 for L2).

template <bool OUT_F32>
__global__ __launch_bounds__(256) void k_gather(
    const int* __restrict__ cursor, const int* __restrict__ deg_a,
    const int* __restrict__ ssrc,
    const unsigned short* __restrict__ gsrc,  // bf16 [N][D]
    void* __restrict__ aggout) {
  const int gid = blockIdx.x * 32 + (threadIdx.x >> 3);  // node
  const int q8 = threadIdx.x & 7;                        // 16B chunk
  if (gid >= N_NODES) return;
  float a[8] = {0.f, 0.f, 0.f, 0.f, 0.f, 0.f, 0.f, 0.f};
  int st = cursor[gid];
  int dg = deg_a[gid];
  int u = 0;
  for (; u + 8 <= dg; u += 8) {
    int s0 = ssrc[st + u + 0], s1 = ssrc[st + u + 1];
    int s2 = ssrc[st + u + 2], s3 = ssrc[st + u + 3];
    int s4 = ssrc[st + u + 4], s5 = ssrc[st + u + 5];
    int s6 = ssrc[st + u + 6], s7 = ssrc[st + u + 7];
    uint4 v0 = *((const uint4*)(gsrc + (long)s0 * D) + q8);
    uint4 v1 = *((const uint4*)(gsrc + (long)s1 * D) + q8);
    uint4 v2 = *((const uint4*)(gsrc + (long)s2 * D) + q8);
    uint4 v3 = *((const uint4*)(gsrc + (long)s3 * D) + q8);
    uint4 v4 = *((const uint4*)(gsrc + (long)s4 * D) + q8);
    uint4 v5 = *((const uint4*)(gsrc + (long)s5 * D) + q8);
    uint4 v6 = *((const uint4*)(gsrc + (long)s6 * D) + q8);
    uint4 v7 = *((const uint4*)(gsrc + (long)s7 * D) + q8);
    add_bf8(a, v0); add_bf8(a, v1); add_bf8(a, v2); add_bf8(a, v3);
    add_bf8(a, v4); add_bf8(a, v5); add_bf8(a, v6); add_bf8(a, v7);
  }
  if (u + 4 <= dg) {
    int s0 = ssrc[st + u + 0], s1 = ssrc[st + u + 1];
    int s2 = ssrc[st + u + 2], s3 = ssrc[st + u + 3];
    uint4 v0 = *((const uint4*)(gsrc + (long)s0 * D) + q8);
    uint4 v1 = *((const uint4*)(gsrc + (long)s1 * D) + q8);
    uint4 v2 = *((const uint4*)(gsrc + (long)s2 * D) + q8);
    uint4 v3 = *((const uint4*)(gsrc + (long)s3 * D) + q8);
    add_bf8(a, v0); add_bf8(a, v1); add_bf8(a, v2); add_bf8(a, v3);
    u += 4;
  }
  for (; u < dg; ++u) {
    uint4 v = *((const uint4*)(gsrc + (long)ssrc[st + u] * D) + q8);
    add_bf8(a, v);
  }
  float invd = 1.0f / fmaxf((float)dg, 1.0f);
#pragma unroll
  for (int j = 0; j < 8; ++j) a[j] *= invd;
  if constexpr (OUT_F32) {
    float* p = (float*)aggout + (long)gid * D + q8 * 8;
    *(float4*)(p + 0) = make_float4(a[0], a[1], a[2], a[3]);
    *(float4*)(p + 4) = make_float4(a[4], a[5], a[6], a[7]);
  } else {
    ushort4 u0, u1;
    u0.x = f2bf_bits(a[0]); u0.y = f2bf_bits(a[1]);
    u0.z = f2bf_bits(a[2]); u0.w = f2bf_bits(a[3]);
    u1.x = f2bf_bits(a[4]); u1.y = f2bf_bits(a[5]);
    u1.z = f2bf_bits(a[6]); u1.w = f2bf_bits(a[7]);
    unsigned short* p = (unsigned short*)aggout + (long)gid * D + q8 * 8;
    *(ushort4*)(p + 0) = u0;
    *(ushort4*)(p + 4) = u1;
  }
}

// ---------------- GEMM + ELU + BN kernel ----------------
// 64-node tile. Stage agg (f32 in LDS; converted from bf16 if needed) + root
// (bf16) via coalesced streaming loads; barrier; SGPR-weight matvec (round-8
// phase-2). For layer 2, agg input and f32 output occupy the SAME d_out rows:
// block t reads exactly the bytes it writes, staged through LDS -> safe.

template <bool AGG_BF16, bool OUT_BF16>
__global__ __launch_bounds__(256) void k_gemm(
    const void* __restrict__ aggp,           // [N][64] bf16 or f32
    const unsigned short* __restrict__ rootp,  // bf16 [N][64]
    const float* __restrict__ wl, const float* __restrict__ bl,
    const float* __restrict__ wr,
    const float* __restrict__ gamma, const float* __restrict__ beta,
    const float* __restrict__ mean, const float* __restrict__ var,
    void* __restrict__ out) {
  __shared__ float ag_t[64 * AGS];           // 17408 B (f32 always)
  __shared__ unsigned short xr_t[64 * XRS];  // 8704 B
  const int tid = threadIdx.x;
  const int base = blockIdx.x * 64;
  const int grp = tid >> 3;  // 32 groups
  const int q8 = tid & 7;

  // stage: 2 passes x 32 rows
  for (int p = 0; p < 2; ++p) {
    int r = p * 32 + grp;
    int n = base + r;
    float a[8] = {0.f, 0.f, 0.f, 0.f, 0.f, 0.f, 0.f, 0.f};
    uint4 rv = make_uint4(0, 0, 0, 0);
    if (n < N_NODES) {
      if constexpr (AGG_BF16) {
        uint4 v = *((const uint4*)((const unsigned short*)aggp + (long)n * D) + q8);
        ushort4 u0 = make_ushort4(v.x & 0xffff, v.x >> 16, v.y & 0xffff, v.y >> 16);
        ushort4 u1 = make_ushort4(v.z & 0xffff, v.z >> 16, v.w & 0xffff, v.w >> 16);
        set_bf8(a, u0, u1);
      } else {
        float4 f0 = *((const float4*)((const float*)aggp + (long)n * D) + q8 * 2);
        float4 f1 = *((const float4*)((const float*)aggp + (long)n * D) + q8 * 2 + 1);
        a[0] = f0.x; a[1] = f0.y; a[2] = f0.z; a[3] = f0.w;
        a[4] = f1.x; a[5] = f1.y; a[6] = f1.z; a[7] = f1.w;
      }
      rv = *((const uint4*)(rootp + (long)n * D) + q8);
    }
    *(float4*)&ag_t[r * AGS + q8 * 8 + 0] = make_float4(a[0], a[1], a[2], a[3]);
    *(float4*)&ag_t[r * AGS + q8 * 8 + 4] = make_float4(a[4], a[5], a[6], a[7]);
    *(uint2*)&xr_t[r * XRS + q8 * 8 + 0] = make_uint2(rv.x, rv.y);
    *(uint2*)&xr_t[r * XRS + q8 * 8 + 4] = make_uint2(rv.z, rv.w);
  }
  __syncthreads();

  // phase 2 (round-8 proven): thread = (node = tid&63, dim-block g = wave)
  const int n = tid & 63;
  const int g = __builtin_amdgcn_readfirstlane(tid >> 6);  // 0..3
  const long gn = base + n;
  const float* arow = &ag_t[n * AGS];
  const unsigned short* xrow = &xr_t[n * XRS];

  for (int dt = 0; dt < 4; ++dt) {
    const int d0 = g * 16 + dt * 4;
    float a0 = bl[d0 + 0], a1 = bl[d0 + 1], a2 = bl[d0 + 2], a3 = bl[d0 + 3];
    const float* w0l = wl + (long)(d0 + 0) * 64;
    const float* w1l = wl + (long)(d0 + 1) * 64;
    const float* w2l = wl + (long)(d0 + 2) * 64;
    const float* w3l = wl + (long)(d0 + 3) * 64;
    const float* w0r = wr + (long)(d0 + 0) * 64;
    const float* w1r = wr + (long)(d0 + 1) * 64;
    const float* w2r = wr + (long)(d0 + 2) * 64;
    const float* w3r = wr + (long)(d0 + 3) * 64;
#pragma unroll
    for (int k = 0; k < 64; k += 8) {
      float4 i0 = *(const float4*)(arow + k);
      float4 i1 = *(const float4*)(arow + k + 4);
      ushort4 u0 = *(const ushort4*)(xrow + k);
      ushort4 u1 = *(const ushort4*)(xrow + k + 4);
      float jr[8];
      set_bf8(jr, u0, u1);
      a0 += i0.x * w0l[k] + i0.y * w0l[k + 1] + i0.z * w0l[k + 2] + i0.w * w0l[k + 3]
          + i1.x * w0l[k + 4] + i1.y * w0l[k + 5] + i1.z * w0l[k + 6] + i1.w * w0l[k + 7]
          + jr[0] * w0r[k] + jr[1] * w0r[k + 1] + jr[2] * w0r[k + 2] + jr[3] * w0r[k + 3]
          + jr[4] * w0r[k + 4] + jr[5] * w0r[k + 5] + jr[6] * w0r[k + 6] + jr[7] * w0r[k + 7];
      a1 += i0.x * w1l[k] + i0.y * w1l[k + 1] + i0.z * w1l[k + 2] + i0.w * w1l[k + 3]
          + i1.x * w1l[k + 4] + i1.y * w1l[k + 5] + i1.z * w1l[k + 6] + i1.w * w1l[k + 7]
          + jr[0] * w1r[k] + jr[1] * w1r[k + 1] + jr[2] * w1r[k + 2] + jr[3] * w1r[k + 3]
          + jr[4] * w1r[k + 4] + jr[5] * w1r[k + 5] + jr[6] * w1r[k + 6] + jr[7] * w1r[k + 7];
      a2 += i0.x * w2l[k] + i0.y * w2l[k + 1] + i0.z * w2l[k + 2] + i0.w * w2l[k + 3]
          + i1.x * w2l[k + 4] + i1.y * w2l[k + 5] + i1.z * w2l[k + 6] + i1.w * w2l[k + 7]
          + jr[0] * w2r[k] + jr[1] * w2r[k + 1] + jr[2] * w2r[k + 2] + jr[3] * w2r[k + 3]
          + jr[4] * w2r[k + 4] + jr[5] * w2r[k + 5] + jr[6] * w2r[k + 6] + jr[7] * w2r[k + 7];
      a3 += i0.x * w3l[k] + i0.y * w3l[k + 1] + i0.z * w3l[k + 2] + i0.w * w3l[k + 3]
          + i1.x * w3l[k + 4] + i1.y * w3l[k + 5] + i1.z * w3l[k + 6] + i1.w * w3l[k + 7]
          + jr[0] * w3r[k] + jr[1] * w3r[k + 1] + jr[2] * w3r[k + 2] + jr[3] * w3r[k + 3]
          + jr[4] * w3r[k + 4] + jr[5] * w3r[k + 5] + jr[6] * w3r[k + 6] + jr[7] * w3r[k + 7];
    }
    if (gn < N_NODES) {
      float sc0 = gamma[d0 + 0] * rsqrtf(var[d0 + 0] + BN_EPS);
      float sc1 = gamma[d0 + 1] * rsqrtf(var[d0 + 1] + BN_EPS);
      float sc2 = gamma[d0 + 2] * rsqrtf(var[d0 + 2] + BN_EPS);
      float sc3 = gamma[d0 + 3] * rsqrtf(var[d0 + 3] + BN_EPS);
      float sh0 = beta[d0 + 0] - mean[d0 + 0] * sc0;
      float sh1 = beta[d0 + 1] - mean[d0 + 1] * sc1;
      float sh2 = beta[d0 + 2] - mean[d0 + 2] * sc2;
      float sh3 = beta[d0 + 3] - mean[d0 + 3] * sc3;
      float o0 = a0 > 0.f ? a0 : expm1f(a0);
      float o1 = a1 > 0.f ? a1 : expm1f(a1);
      float o2 = a2 > 0.f ? a2 : expm1f(a2);
      float o3 = a3 > 0.f ? a3 : expm1f(a3);
      o0 = o0 * sc0 + sh0; o1 = o1 * sc1 + sh1;
      o2 = o2 * sc2 + sh2; o3 = o3 * sc3 + sh3;
      if constexpr (OUT_BF16) {
        ushort4 pk;
        pk.x = f2bf_bits(o0); pk.y = f2bf_bits(o1);
        pk.z = f2bf_bits(o2); pk.w = f2bf_bits(o3);
        *(ushort4*)((unsigned short*)out + gn * D + d0) = pk;
      } else {
        float4 f;
        f.x = o0; f.y = o1; f.z = o2; f.w = o3;
        *(float4*)((float*)out + gn * D + d0) = f;
      }
    }
  }
}

// ---------------- launch ----------------

extern "C" void kernel_launch(void* const* d_in, const int* in_sizes, int n_in,
                              void* d_out, int out_size, void* d_ws, size_t ws_size,
                              hipStream_t stream) {
  const float* x     = (const float*)d_in[0];
  const int*   ei    = (const int*)d_in[1];
  const float* w1_l  = (const float*)d_in[2];
  const float* b1_l  = (const float*)d_in[3];
  const float* w1_r  = (const float*)d_in[4];
  const float* w2_l  = (const float*)d_in[5];
  const float* b2_l  = (const float*)d_in[6];
  const float* w2_r  = (const float*)d_in[7];
  const float* bn1_g = (const float*)d_in[8];
  const float* bn1_b = (const float*)d_in[9];
  const float* bn1_m = (const float*)d_in[10];
  const float* bn1_v = (const float*)d_in[11];
  const float* bn2_g = (const float*)d_in[12];
  const float* bn2_b = (const float*)d_in[13];
  const float* bn2_m = (const float*)d_in[14];
  const float* bn2_v = (const float*)d_in[15];

  // ws layout (20.0 MB, unchanged from round 6):
  int* deg    = (int*)d_ws;          // [N] (+pad, gcount at N)
  int* gcount = deg + N_NODES;       // [1]
  int* cursor = deg + 100008;        // [N] segment starts
  int* ssrc   = cursor + 100008;     // [E]
  unsigned short* h1 = (unsigned short*)(ssrc + N_EDGES);  // bf16 [N*D], 12.8 MB
  int* tmp    = (int*)h1;            // [E] rank|src, aliases h1 (dead until L1)

  // d_out reuse timeline:
  //   aggb1 (bf16 [N][64]) = d_out lower half  -- written by L1 gather
  //   xb    (bf16 [N][64]) = d_out upper half  -- written by k_cvt
  //   L2 gather overwrites ALL of d_out with f32 agg (aggb1/xb dead)
  //   L2 gemm reads+writes the same d_out rows per-tile (LDS-staged, safe)
  unsigned short* aggb1 = (unsigned short*)d_out;
  unsigned short* xb    = (unsigned short*)d_out + (size_t)N_NODES * D;

  const int eb4 = (N_EDGES / 4 + 255) / 256;
  const int gblocks = (N_NODES + 31) / 32;   // 3125: one 8-lane group per node
  const int tiles = (N_NODES + 63) / 64;     // 1563

  hipMemsetAsync(deg, 0, 100008 * sizeof(int), stream);  // deg + gcount
  k_hist_rank<<<eb4, 256, 0, stream>>>(ei, deg, tmp);
  k_offsets<<<NB_SCAN, 256, 0, stream>>>(deg, cursor, gcount);
  k_scatter_rank<<<eb4, 256, 0, stream>>>(ei, tmp, cursor, ssrc);
  k_cvt<<<(N_NODES * D / 4 + 255) / 256, 256, 0, stream>>>(x, xb);

  // layer 1: gather bf16 xb -> bf16 aggb1; gemm(aggb1, xb) -> bf16 h1
  k_gather<false><<<gblocks, 256, 0, stream>>>(cursor, deg, ssrc, xb, aggb1);
  k_gemm<true, true><<<tiles, 256, 0, stream>>>(
      aggb1, xb, w1_l, b1_l, w1_r, bn1_g, bn1_b, bn1_m, bn1_v, h1);

  // layer 2: gather bf16 h1 -> f32 agg in d_out; gemm in-place on d_out
  k_gather<true><<<gblocks, 256, 0, stream>>>(cursor, deg, ssrc, h1, d_out);
  k_gemm<false, false><<<tiles, 256, 0, stream>>>(
      d_out, h1, w2_l, b2_l, w2_r, bn2_g, bn2_b, bn2_m, bn2_v, d_out);
}

// Round 10
// 264.239 us; speedup vs baseline: 1.4174x; 1.3354x over previous
//
#include <hip/hip_runtime.h>
#include <hip/hip_bf16.h>

#define N_NODES 100000
#define N_EDGES 1600000
#define D 64
#define BN_EPS 1e-5f
#define NB_SCAN 391  // ceil(N_NODES/256)

typedef unsigned short u16x8 __attribute__((ext_vector_type(8)));
typedef __bf16 bf16x8 __attribute__((ext_vector_type(8)));
typedef float f32x4 __attribute__((ext_vector_type(4)));

// ---------------- CSR build (round-6 proven) ----------------

__global__ __launch_bounds__(256) void k_hist_rank(const int* __restrict__ ei,
                                                   int* __restrict__ deg,
                                                   int* __restrict__ tmp) {
  int e = (blockIdx.x * 256 + threadIdx.x) * 4;
  if (e >= N_EDGES) return;
  int4 s = *(const int4*)(ei + e);
  int4 d = *(const int4*)(ei + N_EDGES + e);
  int4 t;
  t.x = s.x | (atomicAdd(&deg[d.x], 1) << 17);
  t.y = s.y | (atomicAdd(&deg[d.y], 1) << 17);
  t.z = s.z | (atomicAdd(&deg[d.z], 1) << 17);
  t.w = s.w | (atomicAdd(&deg[d.w], 1) << 17);
  *(int4*)(tmp + e) = t;
}

__global__ __launch_bounds__(256) void k_offsets(const int* __restrict__ deg,
                                                 int* __restrict__ cursor,
                                                 int* __restrict__ gcount) {
  __shared__ int sd[256];
  __shared__ int sbase;
  int tid = threadIdx.x;
  int i = blockIdx.x * 256 + tid;
  int v = (i < N_NODES) ? deg[i] : 0;
  sd[tid] = v;
  __syncthreads();
  for (int ofs = 1; ofs < 256; ofs <<= 1) {
    int t = (tid >= ofs) ? sd[tid - ofs] : 0;
    __syncthreads();
    sd[tid] += t;
    __syncthreads();
  }
  if (tid == 255) sbase = atomicAdd(gcount, sd[255]);
  __syncthreads();
  if (i < N_NODES) cursor[i] = sbase + sd[tid] - v;  // exclusive segment start
}

__global__ __launch_bounds__(256) void k_scatter_rank(const int* __restrict__ ei,
                                                      const int* __restrict__ tmp,
                                                      const int* __restrict__ cursor,
                                                      int* __restrict__ ssrc) {
  int e = (blockIdx.x * 256 + threadIdx.x) * 4;
  if (e >= N_EDGES) return;
  int4 d = *(const int4*)(ei + N_EDGES + e);
  int4 t = *(const int4*)(tmp + e);
  ssrc[cursor[d.x] + ((unsigned)t.x >> 17)] = t.x & 0x1ffff;
  ssrc[cursor[d.y] + ((unsigned)t.y >> 17)] = t.y & 0x1ffff;
  ssrc[cursor[d.z] + ((unsigned)t.z >> 17)] = t.z & 0x1ffff;
  ssrc[cursor[d.w] + ((unsigned)t.w >> 17)] = t.w & 0x1ffff;
}

// ---------------- helpers ----------------

static __device__ inline unsigned short f2bf_bits(float v) {
  __hip_bfloat16 h = __float2bfloat16(v);
  return *reinterpret_cast<unsigned short*>(&h);
}

// add 8 bf16 (one uint4 = 16B) into f32 accumulators
static __device__ inline void add_bf8(float* a, uint4 v) {
  unsigned int b;
  b = v.x << 16;         a[0] += *(float*)&b;
  b = v.x & 0xffff0000u; a[1] += *(float*)&b;
  b = v.y << 16;         a[2] += *(float*)&b;
  b = v.y & 0xffff0000u; a[3] += *(float*)&b;
  b = v.z << 16;         a[4] += *(float*)&b;
  b = v.z & 0xffff0000u; a[5] += *(float*)&b;
  b = v.w << 16;         a[6] += *(float*)&b;
  b = v.w & 0xffff0000u; a[7] += *(float*)&b;
}

// x f32 -> bf16 copy (into upper half of d_out; dead until L2 gather rewrites)
__global__ __launch_bounds__(256) void k_cvt(const float* __restrict__ x,
                                             unsigned short* __restrict__ xb) {
  long i = (long)(blockIdx.x * 256 + threadIdx.x) * 4;
  if (i >= (long)N_NODES * D) return;
  float4 v = *(const float4*)(x + i);
  ushort4 u;
  u.x = f2bf_bits(v.x); u.y = f2bf_bits(v.y);
  u.z = f2bf_bits(v.z); u.w = f2bf_bits(v.w);
  *(ushort4*)(xb + i) = u;
}

// ---------------- pure gather kernel (round-9 proven) ----------------

template <bool OUT_F32>
__global__ __launch_bounds__(256) void k_gather(
    const int* __restrict__ cursor, const int* __restrict__ deg_a,
    const int* __restrict__ ssrc,
    const unsigned short* __restrict__ gsrc,  // bf16 [N][D]
    void* __restrict__ aggout) {
  const int gid = blockIdx.x * 32 + (threadIdx.x >> 3);  // node
  const int q8 = threadIdx.x & 7;                        // 16B chunk
  if (gid >= N_NODES) return;
  float a[8] = {0.f, 0.f, 0.f, 0.f, 0.f, 0.f, 0.f, 0.f};
  int st = cursor[gid];
  int dg = deg_a[gid];
  int u = 0;
  for (; u + 8 <= dg; u += 8) {
    int s0 = ssrc[st + u + 0], s1 = ssrc[st + u + 1];
    int s2 = ssrc[st + u + 2], s3 = ssrc[st + u + 3];
    int s4 = ssrc[st + u + 4], s5 = ssrc[st + u + 5];
    int s6 = ssrc[st + u + 6], s7 = ssrc[st + u + 7];
    uint4 v0 = *((const uint4*)(gsrc + (long)s0 * D) + q8);
    uint4 v1 = *((const uint4*)(gsrc + (long)s1 * D) + q8);
    uint4 v2 = *((const uint4*)(gsrc + (long)s2 * D) + q8);
    uint4 v3 = *((const uint4*)(gsrc + (long)s3 * D) + q8);
    uint4 v4 = *((const uint4*)(gsrc + (long)s4 * D) + q8);
    uint4 v5 = *((const uint4*)(gsrc + (long)s5 * D) + q8);
    uint4 v6 = *((const uint4*)(gsrc + (long)s6 * D) + q8);
    uint4 v7 = *((const uint4*)(gsrc + (long)s7 * D) + q8);
    add_bf8(a, v0); add_bf8(a, v1); add_bf8(a, v2); add_bf8(a, v3);
    add_bf8(a, v4); add_bf8(a, v5); add_bf8(a, v6); add_bf8(a, v7);
  }
  if (u + 4 <= dg) {
    int s0 = ssrc[st + u + 0], s1 = ssrc[st + u + 1];
    int s2 = ssrc[st + u + 2], s3 = ssrc[st + u + 3];
    uint4 v0 = *((const uint4*)(gsrc + (long)s0 * D) + q8);
    uint4 v1 = *((const uint4*)(gsrc + (long)s1 * D) + q8);
    uint4 v2 = *((const uint4*)(gsrc + (long)s2 * D) + q8);
    uint4 v3 = *((const uint4*)(gsrc + (long)s3 * D) + q8);
    add_bf8(a, v0); add_bf8(a, v1); add_bf8(a, v2); add_bf8(a, v3);
    u += 4;
  }
  for (; u < dg; ++u) {
    uint4 v = *((const uint4*)(gsrc + (long)ssrc[st + u] * D) + q8);
    add_bf8(a, v);
  }
  float invd = 1.0f / fmaxf((float)dg, 1.0f);
#pragma unroll
  for (int j = 0; j < 8; ++j) a[j] *= invd;
  if constexpr (OUT_F32) {
    float* p = (float*)aggout + (long)gid * D + q8 * 8;
    *(float4*)(p + 0) = make_float4(a[0], a[1], a[2], a[3]);
    *(float4*)(p + 4) = make_float4(a[4], a[5], a[6], a[7]);
  } else {
    ushort4 u0, u1;
    u0.x = f2bf_bits(a[0]); u0.y = f2bf_bits(a[1]);
    u0.z = f2bf_bits(a[2]); u0.w = f2bf_bits(a[3]);
    u1.x = f2bf_bits(a[4]); u1.y = f2bf_bits(a[5]);
    u1.z = f2bf_bits(a[6]); u1.w = f2bf_bits(a[7]);
    unsigned short* p = (unsigned short*)aggout + (long)gid * D + q8 * 8;
    *(ushort4*)(p + 0) = u0;
    *(ushort4*)(p + 4) = u1;
  }
}

// ---------------- MFMA GEMM + ELU + BN ----------------
// Per wave: 16 nodes x 64 outputs, K=128 ([agg|root] @ [Wl;Wr]^T).
// 16x16x32 bf16 MFMA. Fragment layout (m89-verified):
//   A: row = lane&15, k = (lane>>4)*8 + j     (u16x8 = 16B load per frag)
//   B: col = lane&15, k = (lane>>4)*8 + j     (from W[col][k], bf16-converted)
//   D: col = lane&15, row = (lane>>4)*4 + r
// No LDS. Weights read per-wave (L1-hot, 32KB total). Layer 2 runs in-place
// on d_out: each wave reads exactly the f32 agg rows it later overwrites
// (D-row independence => clamped OOB rows pollute nothing).

template <bool AGG_F32, bool OUT_BF16>
__global__ __launch_bounds__(256) void k_gemm_mfma(
    const void* __restrict__ aggp,             // [N][64] bf16 or f32
    const unsigned short* __restrict__ rootp,  // bf16 [N][64]
    const float* __restrict__ wl, const float* __restrict__ bl,
    const float* __restrict__ wr,
    const float* __restrict__ gamma, const float* __restrict__ beta,
    const float* __restrict__ mean, const float* __restrict__ var,
    void* __restrict__ out) {
  const int tid = threadIdx.x;
  const int lane = tid & 63;
  const int wv = tid >> 6;       // 0..3
  const int c16 = lane & 15;     // A-row / B-col / D-col selector
  const int kg = lane >> 4;      // 0..3 (k-slice / D-row-group)
  const int node0 = blockIdx.x * 64 + wv * 16;

  // ---- B fragments: bfr[kt][ot]; kt: K-tile (0,1 -> Wl; 2,3 -> Wr)
  bf16x8 bfr[4][4];
#pragma unroll
  for (int kt = 0; kt < 4; ++kt) {
    const float* wsrc = (kt < 2) ? wl : wr;
    const int kofs = (kt & 1) * 32 + kg * 8;
#pragma unroll
    for (int ot = 0; ot < 4; ++ot) {
      const float* p = wsrc + (long)(ot * 16 + c16) * 64 + kofs;
      float4 f0 = *(const float4*)p;
      float4 f1 = *(const float4*)(p + 4);
      u16x8 u;
      u[0] = f2bf_bits(f0.x); u[1] = f2bf_bits(f0.y);
      u[2] = f2bf_bits(f0.z); u[3] = f2bf_bits(f0.w);
      u[4] = f2bf_bits(f1.x); u[5] = f2bf_bits(f1.y);
      u[6] = f2bf_bits(f1.z); u[7] = f2bf_bits(f1.w);
      bfr[kt][ot] = __builtin_bit_cast(bf16x8, u);
    }
  }

  // ---- A fragments: afr[kt]; node row = node0 + c16 (clamped if OOB)
  long nrow = node0 + c16;
  long nclamp = (nrow < N_NODES) ? nrow : (N_NODES - 1);
  bf16x8 afr[4];
  if constexpr (AGG_F32) {
    const float* ap = (const float*)aggp + nclamp * D;
#pragma unroll
    for (int kt = 0; kt < 2; ++kt) {
      float4 f0 = *(const float4*)(ap + kt * 32 + kg * 8);
      float4 f1 = *(const float4*)(ap + kt * 32 + kg * 8 + 4);
      u16x8 u;
      u[0] = f2bf_bits(f0.x); u[1] = f2bf_bits(f0.y);
      u[2] = f2bf_bits(f0.z); u[3] = f2bf_bits(f0.w);
      u[4] = f2bf_bits(f1.x); u[5] = f2bf_bits(f1.y);
      u[6] = f2bf_bits(f1.z); u[7] = f2bf_bits(f1.w);
      afr[kt] = __builtin_bit_cast(bf16x8, u);
    }
  } else {
    const unsigned short* ap = (const unsigned short*)aggp + nclamp * D;
    afr[0] = __builtin_bit_cast(bf16x8, *(const u16x8*)(ap + kg * 8));
    afr[1] = __builtin_bit_cast(bf16x8, *(const u16x8*)(ap + 32 + kg * 8));
  }
  {
    const unsigned short* rp = rootp + nclamp * D;
    afr[2] = __builtin_bit_cast(bf16x8, *(const u16x8*)(rp + kg * 8));
    afr[3] = __builtin_bit_cast(bf16x8, *(const u16x8*)(rp + 32 + kg * 8));
  }

  // ---- MFMA: acc[ot] over 4 K-tiles
  f32x4 acc[4];
#pragma unroll
  for (int ot = 0; ot < 4; ++ot) acc[ot] = (f32x4){0.f, 0.f, 0.f, 0.f};
#pragma unroll
  for (int ot = 0; ot < 4; ++ot)
#pragma unroll
    for (int kt = 0; kt < 4; ++kt)
      acc[ot] = __builtin_amdgcn_mfma_f32_16x16x32_bf16(afr[kt], bfr[kt][ot],
                                                        acc[ot], 0, 0, 0);

  // ---- epilogue: +bias, ELU, BN; store D[row=4*kg+r][col=ot*16+c16]
  float scv[4], shv[4], blv[4];
#pragma unroll
  for (int ot = 0; ot < 4; ++ot) {
    int ch = ot * 16 + c16;
    float sc = gamma[ch] * rsqrtf(var[ch] + BN_EPS);
    scv[ot] = sc;
    shv[ot] = beta[ch] - mean[ch] * sc;
    blv[ot] = bl[ch];
  }
#pragma unroll
  for (int r = 0; r < 4; ++r) {
    long node_out = node0 + kg * 4 + r;
    if (node_out < N_NODES) {
#pragma unroll
      for (int ot = 0; ot < 4; ++ot) {
        float v = acc[ot][r] + blv[ot];
        v = v > 0.f ? v : expm1f(v);
        v = v * scv[ot] + shv[ot];
        if constexpr (OUT_BF16) {
          ((unsigned short*)out)[node_out * D + ot * 16 + c16] = f2bf_bits(v);
        } else {
          ((float*)out)[node_out * D + ot * 16 + c16] = v;
        }
      }
    }
  }
}

// ---------------- launch ----------------

extern "C" void kernel_launch(void* const* d_in, const int* in_sizes, int n_in,
                              void* d_out, int out_size, void* d_ws, size_t ws_size,
                              hipStream_t stream) {
  const float* x     = (const float*)d_in[0];
  const int*   ei    = (const int*)d_in[1];
  const float* w1_l  = (const float*)d_in[2];
  const float* b1_l  = (const float*)d_in[3];
  const float* w1_r  = (const float*)d_in[4];
  const float* w2_l  = (const float*)d_in[5];
  const float* b2_l  = (const float*)d_in[6];
  const float* w2_r  = (const float*)d_in[7];
  const float* bn1_g = (const float*)d_in[8];
  const float* bn1_b = (const float*)d_in[9];
  const float* bn1_m = (const float*)d_in[10];
  const float* bn1_v = (const float*)d_in[11];
  const float* bn2_g = (const float*)d_in[12];
  const float* bn2_b = (const float*)d_in[13];
  const float* bn2_m = (const float*)d_in[14];
  const float* bn2_v = (const float*)d_in[15];

  // ws layout (20.0 MB):
  int* deg    = (int*)d_ws;          // [N] (+pad, gcount at N)
  int* gcount = deg + N_NODES;       // [1]
  int* cursor = deg + 100008;        // [N] segment starts
  int* ssrc   = cursor + 100008;     // [E]
  unsigned short* h1 = (unsigned short*)(ssrc + N_EDGES);  // bf16 [N*D], 12.8 MB
  int* tmp    = (int*)h1;            // [E] rank|src, aliases h1 (dead until L1)

  // d_out reuse timeline (round-9 proven):
  //   aggb1 = d_out lower half (bf16 agg, L1); xb = upper half (bf16 x)
  //   L2 gather overwrites ALL of d_out with f32 agg; L2 gemm in-place.
  unsigned short* aggb1 = (unsigned short*)d_out;
  unsigned short* xb    = (unsigned short*)d_out + (size_t)N_NODES * D;

  const int eb4 = (N_EDGES / 4 + 255) / 256;
  const int gblocks = (N_NODES + 31) / 32;   // 3125
  const int tiles = (N_NODES + 63) / 64;     // 1563

  hipMemsetAsync(deg, 0, 100008 * sizeof(int), stream);  // deg + gcount
  k_hist_rank<<<eb4, 256, 0, stream>>>(ei, deg, tmp);
  k_offsets<<<NB_SCAN, 256, 0, stream>>>(deg, cursor, gcount);
  k_scatter_rank<<<eb4, 256, 0, stream>>>(ei, tmp, cursor, ssrc);
  k_cvt<<<(N_NODES * D / 4 + 255) / 256, 256, 0, stream>>>(x, xb);

  // layer 1: gather bf16 xb -> bf16 aggb1; MFMA gemm(aggb1, xb) -> bf16 h1
  k_gather<false><<<gblocks, 256, 0, stream>>>(cursor, deg, ssrc, xb, aggb1);
  k_gemm_mfma<false, true><<<tiles, 256, 0, stream>>>(
      aggb1, xb, w1_l, b1_l, w1_r, bn1_g, bn1_b, bn1_m, bn1_v, h1);

  // layer 2: gather bf16 h1 -> f32 agg in d_out; MFMA gemm in-place on d_out
  k_gather<true><<<gblocks, 256, 0, stream>>>(cursor, deg, ssrc, h1, d_out);
  k_gemm_mfma<true, false><<<tiles, 256, 0, stream>>>(
      d_out, h1, w2_l, b2_l, w2_r, bn2_g, bn2_b, bn2_m, bn2_v, d_out);
}

// Round 11
// 196.072 us; speedup vs baseline: 1.9102x; 1.3477x over previous
//
#include <hip/hip_runtime.h>
#include <hip/hip_bf16.h>

#define N_NODES 100000
#define N_EDGES 1600000
#define D 64
#define BN_EPS 1e-5f
#define NBKT 391   // buckets of 256 nodes: ceil(100000/256)
#define EPB 1024   // edges per block in pass A/B
#define EB 1563    // ceil(N_EDGES/EPB)

typedef unsigned short u16x8 __attribute__((ext_vector_type(8)));
typedef __bf16 bf16x8 __attribute__((ext_vector_type(8)));
typedef float f32x4 __attribute__((ext_vector_type(4)));

// ---------------- CSR build, atomic-free at global scope ----------------
// Round-10 lesson: global atomicAdd write-throughs ~32B/op -> 50+ MB of HBM
// write traffic for 1.6M atomics. Replace with bucketed build: LDS atomics
// for counting, scans for placement.

// Pass A: per-block bucket histogram (LDS) -> relbase[bucket][block]
__global__ __launch_bounds__(256) void k_bcount(const int* __restrict__ ei,
                                                int* __restrict__ relbase) {
  __shared__ int h[NBKT];
  const int tid = threadIdx.x;
  for (int i = tid; i < NBKT; i += 256) h[i] = 0;
  __syncthreads();
  int e = blockIdx.x * EPB + tid * 4;
  if (e < N_EDGES) {  // N_EDGES%4==0 -> full int4 safe
    int4 d = *(const int4*)(ei + N_EDGES + e);
    atomicAdd(&h[d.x >> 8], 1);
    atomicAdd(&h[d.y >> 8], 1);
    atomicAdd(&h[d.z >> 8], 1);
    atomicAdd(&h[d.w >> 8], 1);
  }
  __syncthreads();
  for (int i = tid; i < NBKT; i += 256)
    relbase[i * EB + blockIdx.x] = h[i];  // bucket-major
}

// Scan 1: per bucket, exclusive scan over blocks; total -> bktsum
__global__ __launch_bounds__(256) void k_scan_bkt(int* __restrict__ relbase,
                                                  int* __restrict__ bktsum) {
  __shared__ int sd[256];
  __shared__ int carry;
  const int i = blockIdx.x;
  const int tid = threadIdx.x;
  if (tid == 0) carry = 0;
  __syncthreads();
  int* p = relbase + i * EB;
  for (int c0 = 0; c0 < EB; c0 += 256) {
    int idx = c0 + tid;
    int v = (idx < EB) ? p[idx] : 0;
    sd[tid] = v;
    __syncthreads();
    for (int ofs = 1; ofs < 256; ofs <<= 1) {
      int t = (tid >= ofs) ? sd[tid - ofs] : 0;
      __syncthreads();
      sd[tid] += t;
      __syncthreads();
    }
    int excl = carry + sd[tid] - v;
    if (idx < EB) p[idx] = excl;
    __syncthreads();
    if (tid == 255) carry += sd[255];
    __syncthreads();
  }
  if (tid == 0) bktsum[i] = carry;
}

// Scan 2: exclusive scan of bucket totals -> bktstart
__global__ __launch_bounds__(512) void k_scan_start(const int* __restrict__ bktsum,
                                                    int* __restrict__ bktstart) {
  __shared__ int sd[512];
  const int tid = threadIdx.x;
  int v = (tid < NBKT) ? bktsum[tid] : 0;
  sd[tid] = v;
  __syncthreads();
  for (int ofs = 1; ofs < 512; ofs <<= 1) {
    int t = (tid >= ofs) ? sd[tid - ofs] : 0;
    __syncthreads();
    sd[tid] += t;
    __syncthreads();
  }
  if (tid < NBKT) bktstart[tid] = sd[tid] - v;
}

// Pass B: group edges by bucket; position = bktstart + relbase + LDS rank.
// grouped[e] = src | (dst&255)<<17  (src < 2^17, local node id 8 bits)
__global__ __launch_bounds__(256) void k_group(const int* __restrict__ ei,
                                               const int* __restrict__ relbase,
                                               const int* __restrict__ bktstart,
                                               int* __restrict__ grouped) {
  __shared__ int cur[NBKT];
  const int tid = threadIdx.x;
  const int b = blockIdx.x;
  for (int i = tid; i < NBKT; i += 256)
    cur[i] = bktstart[i] + relbase[i * EB + b];
  __syncthreads();
  int e = b * EPB + tid * 4;
  if (e < N_EDGES) {
    int4 s = *(const int4*)(ei + e);
    int4 d = *(const int4*)(ei + N_EDGES + e);
    int p;
    p = atomicAdd(&cur[d.x >> 8], 1); grouped[p] = s.x | ((d.x & 255) << 17);
    p = atomicAdd(&cur[d.y >> 8], 1); grouped[p] = s.y | ((d.y & 255) << 17);
    p = atomicAdd(&cur[d.z >> 8], 1); grouped[p] = s.z | ((d.z & 255) << 17);
    p = atomicAdd(&cur[d.w >> 8], 1); grouped[p] = s.w | ((d.w & 255) << 17);
  }
}

// Pass C: per bucket (256 nodes): LDS count + scan + place -> deg, cursor
// (global segment start), ssrc. No global atomics, no memset needed.
__global__ __launch_bounds__(256) void k_build(const int* __restrict__ grouped,
                                               const int* __restrict__ bktstart,
                                               const int* __restrict__ bktsum,
                                               int* __restrict__ deg,
                                               int* __restrict__ cursor,
                                               int* __restrict__ ssrc) {
  __shared__ int cnt[256];
  __shared__ int sloc[256];
  __shared__ int cur2[256];
  const int i = blockIdx.x;
  const int tid = threadIdx.x;
  const int gstart = bktstart[i];
  const int gnum = bktsum[i];
  cnt[tid] = 0;
  __syncthreads();
  for (int j = tid; j < gnum; j += 256)
    atomicAdd(&cnt[((unsigned)grouped[gstart + j]) >> 17], 1);
  __syncthreads();
  int v = cnt[tid];
  sloc[tid] = v;
  __syncthreads();
  for (int ofs = 1; ofs < 256; ofs <<= 1) {
    int t = (tid >= ofs) ? sloc[tid - ofs] : 0;
    __syncthreads();
    sloc[tid] += t;
    __syncthreads();
  }
  int excl = sloc[tid] - v;
  int node = i * 256 + tid;
  if (node < N_NODES) {
    deg[node] = v;
    cursor[node] = gstart + excl;
  }
  cur2[tid] = gstart + excl;
  __syncthreads();
  for (int j = tid; j < gnum; j += 256) {
    int g = grouped[gstart + j];
    int p = atomicAdd(&cur2[((unsigned)g) >> 17], 1);
    ssrc[p] = g & 0x1ffff;
  }
}

// ---------------- helpers ----------------

static __device__ inline unsigned short f2bf_bits(float v) {
  __hip_bfloat16 h = __float2bfloat16(v);
  return *reinterpret_cast<unsigned short*>(&h);
}

static __device__ inline void add_bf8(float* a, uint4 v) {
  unsigned int b;
  b = v.x << 16;         a[0] += *(float*)&b;
  b = v.x & 0xffff0000u; a[1] += *(float*)&b;
  b = v.y << 16;         a[2] += *(float*)&b;
  b = v.y & 0xffff0000u; a[3] += *(float*)&b;
  b = v.z << 16;         a[4] += *(float*)&b;
  b = v.z & 0xffff0000u; a[5] += *(float*)&b;
  b = v.w << 16;         a[6] += *(float*)&b;
  b = v.w & 0xffff0000u; a[7] += *(float*)&b;
}

__global__ __launch_bounds__(256) void k_cvt(const float* __restrict__ x,
                                             unsigned short* __restrict__ xb) {
  long i = (long)(blockIdx.x * 256 + threadIdx.x) * 4;
  if (i >= (long)N_NODES * D) return;
  float4 v = *(const float4*)(x + i);
  ushort4 u;
  u.x = f2bf_bits(v.x); u.y = f2bf_bits(v.y);
  u.z = f2bf_bits(v.z); u.w = f2bf_bits(v.w);
  *(ushort4*)(xb + i) = u;
}

// ---------------- pure gather kernel (round-9 proven) ----------------

template <bool OUT_F32>
__global__ __launch_bounds__(256) void k_gather(
    const int* __restrict__ cursor, const int* __restrict__ deg_a,
    const int* __restrict__ ssrc,
    const unsigned short* __restrict__ gsrc,  // bf16 [N][D]
    void* __restrict__ aggout) {
  const int gid = blockIdx.x * 32 + (threadIdx.x >> 3);  // node
  const int q8 = threadIdx.x & 7;                        // 16B chunk
  if (gid >= N_NODES) return;
  float a[8] = {0.f, 0.f, 0.f, 0.f, 0.f, 0.f, 0.f, 0.f};
  int st = cursor[gid];
  int dg = deg_a[gid];
  int u = 0;
  for (; u + 8 <= dg; u += 8) {
    int s0 = ssrc[st + u + 0], s1 = ssrc[st + u + 1];
    int s2 = ssrc[st + u + 2], s3 = ssrc[st + u + 3];
    int s4 = ssrc[st + u + 4], s5 = ssrc[st + u + 5];
    int s6 = ssrc[st + u + 6], s7 = ssrc[st + u + 7];
    uint4 v0 = *((const uint4*)(gsrc + (long)s0 * D) + q8);
    uint4 v1 = *((const uint4*)(gsrc + (long)s1 * D) + q8);
    uint4 v2 = *((const uint4*)(gsrc + (long)s2 * D) + q8);
    uint4 v3 = *((const uint4*)(gsrc + (long)s3 * D) + q8);
    uint4 v4 = *((const uint4*)(gsrc + (long)s4 * D) + q8);
    uint4 v5 = *((const uint4*)(gsrc + (long)s5 * D) + q8);
    uint4 v6 = *((const uint4*)(gsrc + (long)s6 * D) + q8);
    uint4 v7 = *((const uint4*)(gsrc + (long)s7 * D) + q8);
    add_bf8(a, v0); add_bf8(a, v1); add_bf8(a, v2); add_bf8(a, v3);
    add_bf8(a, v4); add_bf8(a, v5); add_bf8(a, v6); add_bf8(a, v7);
  }
  if (u + 4 <= dg) {
    int s0 = ssrc[st + u + 0], s1 = ssrc[st + u + 1];
    int s2 = ssrc[st + u + 2], s3 = ssrc[st + u + 3];
    uint4 v0 = *((const uint4*)(gsrc + (long)s0 * D) + q8);
    uint4 v1 = *((const uint4*)(gsrc + (long)s1 * D) + q8);
    uint4 v2 = *((const uint4*)(gsrc + (long)s2 * D) + q8);
    uint4 v3 = *((const uint4*)(gsrc + (long)s3 * D) + q8);
    add_bf8(a, v0); add_bf8(a, v1); add_bf8(a, v2); add_bf8(a, v3);
    u += 4;
  }
  for (; u < dg; ++u) {
    uint4 v = *((const uint4*)(gsrc + (long)ssrc[st + u] * D) + q8);
    add_bf8(a, v);
  }
  float invd = 1.0f / fmaxf((float)dg, 1.0f);
#pragma unroll
  for (int j = 0; j < 8; ++j) a[j] *= invd;
  if constexpr (OUT_F32) {
    float* p = (float*)aggout + (long)gid * D + q8 * 8;
    *(float4*)(p + 0) = make_float4(a[0], a[1], a[2], a[3]);
    *(float4*)(p + 4) = make_float4(a[4], a[5], a[6], a[7]);
  } else {
    ushort4 u0, u1;
    u0.x = f2bf_bits(a[0]); u0.y = f2bf_bits(a[1]);
    u0.z = f2bf_bits(a[2]); u0.w = f2bf_bits(a[3]);
    u1.x = f2bf_bits(a[4]); u1.y = f2bf_bits(a[5]);
    u1.z = f2bf_bits(a[6]); u1.w = f2bf_bits(a[7]);
    unsigned short* p = (unsigned short*)aggout + (long)gid * D + q8 * 8;
    *(ushort4*)(p + 0) = u0;
    *(ushort4*)(p + 4) = u1;
  }
}

// ---------------- MFMA GEMM + ELU + BN (round-10 proven) ----------------

template <bool AGG_F32, bool OUT_BF16>
__global__ __launch_bounds__(256) void k_gemm_mfma(
    const void* __restrict__ aggp,             // [N][64] bf16 or f32
    const unsigned short* __restrict__ rootp,  // bf16 [N][64]
    const float* __restrict__ wl, const float* __restrict__ bl,
    const float* __restrict__ wr,
    const float* __restrict__ gamma, const float* __restrict__ beta,
    const float* __restrict__ mean, const float* __restrict__ var,
    void* __restrict__ out) {
  const int tid = threadIdx.x;
  const int lane = tid & 63;
  const int wv = tid >> 6;
  const int c16 = lane & 15;
  const int kg = lane >> 4;
  const int node0 = blockIdx.x * 64 + wv * 16;

  bf16x8 bfr[4][4];
#pragma unroll
  for (int kt = 0; kt < 4; ++kt) {
    const float* wsrc = (kt < 2) ? wl : wr;
    const int kofs = (kt & 1) * 32 + kg * 8;
#pragma unroll
    for (int ot = 0; ot < 4; ++ot) {
      const float* p = wsrc + (long)(ot * 16 + c16) * 64 + kofs;
      float4 f0 = *(const float4*)p;
      float4 f1 = *(const float4*)(p + 4);
      u16x8 u;
      u[0] = f2bf_bits(f0.x); u[1] = f2bf_bits(f0.y);
      u[2] = f2bf_bits(f0.z); u[3] = f2bf_bits(f0.w);
      u[4] = f2bf_bits(f1.x); u[5] = f2bf_bits(f1.y);
      u[6] = f2bf_bits(f1.z); u[7] = f2bf_bits(f1.w);
      bfr[kt][ot] = __builtin_bit_cast(bf16x8, u);
    }
  }

  long nrow = node0 + c16;
  long nclamp = (nrow < N_NODES) ? nrow : (N_NODES - 1);
  bf16x8 afr[4];
  if constexpr (AGG_F32) {
    const float* ap = (const float*)aggp + nclamp * D;
#pragma unroll
    for (int kt = 0; kt < 2; ++kt) {
      float4 f0 = *(const float4*)(ap + kt * 32 + kg * 8);
      float4 f1 = *(const float4*)(ap + kt * 32 + kg * 8 + 4);
      u16x8 u;
      u[0] = f2bf_bits(f0.x); u[1] = f2bf_bits(f0.y);
      u[2] = f2bf_bits(f0.z); u[3] = f2bf_bits(f0.w);
      u[4] = f2bf_bits(f1.x); u[5] = f2bf_bits(f1.y);
      u[6] = f2bf_bits(f1.z); u[7] = f2bf_bits(f1.w);
      afr[kt] = __builtin_bit_cast(bf16x8, u);
    }
  } else {
    const unsigned short* ap = (const unsigned short*)aggp + nclamp * D;
    afr[0] = __builtin_bit_cast(bf16x8, *(const u16x8*)(ap + kg * 8));
    afr[1] = __builtin_bit_cast(bf16x8, *(const u16x8*)(ap + 32 + kg * 8));
  }
  {
    const unsigned short* rp = rootp + nclamp * D;
    afr[2] = __builtin_bit_cast(bf16x8, *(const u16x8*)(rp + kg * 8));
    afr[3] = __builtin_bit_cast(bf16x8, *(const u16x8*)(rp + 32 + kg * 8));
  }

  f32x4 acc[4];
#pragma unroll
  for (int ot = 0; ot < 4; ++ot) acc[ot] = (f32x4){0.f, 0.f, 0.f, 0.f};
#pragma unroll
  for (int ot = 0; ot < 4; ++ot)
#pragma unroll
    for (int kt = 0; kt < 4; ++kt)
      acc[ot] = __builtin_amdgcn_mfma_f32_16x16x32_bf16(afr[kt], bfr[kt][ot],
                                                        acc[ot], 0, 0, 0);

  float scv[4], shv[4], blv[4];
#pragma unroll
  for (int ot = 0; ot < 4; ++ot) {
    int ch = ot * 16 + c16;
    float sc = gamma[ch] * rsqrtf(var[ch] + BN_EPS);
    scv[ot] = sc;
    shv[ot] = beta[ch] - mean[ch] * sc;
    blv[ot] = bl[ch];
  }
#pragma unroll
  for (int r = 0; r < 4; ++r) {
    long node_out = node0 + kg * 4 + r;
    if (node_out < N_NODES) {
#pragma unroll
      for (int ot = 0; ot < 4; ++ot) {
        float v = acc[ot][r] + blv[ot];
        v = v > 0.f ? v : expm1f(v);
        v = v * scv[ot] + shv[ot];
        if constexpr (OUT_BF16) {
          ((unsigned short*)out)[node_out * D + ot * 16 + c16] = f2bf_bits(v);
        } else {
          ((float*)out)[node_out * D + ot * 16 + c16] = v;
        }
      }
    }
  }
}

// ---------------- launch ----------------

extern "C" void kernel_launch(void* const* d_in, const int* in_sizes, int n_in,
                              void* d_out, int out_size, void* d_ws, size_t ws_size,
                              hipStream_t stream) {
  const float* x     = (const float*)d_in[0];
  const int*   ei    = (const int*)d_in[1];
  const float* w1_l  = (const float*)d_in[2];
  const float* b1_l  = (const float*)d_in[3];
  const float* w1_r  = (const float*)d_in[4];
  const float* w2_l  = (const float*)d_in[5];
  const float* b2_l  = (const float*)d_in[6];
  const float* w2_r  = (const float*)d_in[7];
  const float* bn1_g = (const float*)d_in[8];
  const float* bn1_b = (const float*)d_in[9];
  const float* bn1_m = (const float*)d_in[10];
  const float* bn1_v = (const float*)d_in[11];
  const float* bn2_g = (const float*)d_in[12];
  const float* bn2_b = (const float*)d_in[13];
  const float* bn2_m = (const float*)d_in[14];
  const float* bn2_v = (const float*)d_in[15];

  // ws layout (~20.0 MB):
  int* deg      = (int*)d_ws;            // [100096]
  int* cursor   = deg + 100096;          // [100096] segment starts
  int* bktsum   = cursor + 100096;       // [512]
  int* bktstart = bktsum + 512;          // [512]
  int* ssrc     = bktstart + 512;        // [E]
  unsigned short* h1 = (unsigned short*)(ssrc + N_EDGES);  // bf16 [N*D], 12.8 MB
  int* grouped  = (int*)h1;              // [E] aliases h1 (dead until L1 gemm)
  int* relbase  = grouped + N_EDGES;     // [NBKT*EB] 2.44 MB, also aliases h1

  // d_out reuse (round-9/10 proven): aggb1 = lower half, xb = upper half;
  // L2 gather overwrites all of d_out with f32 agg; L2 gemm in-place.
  unsigned short* aggb1 = (unsigned short*)d_out;
  unsigned short* xb    = (unsigned short*)d_out + (size_t)N_NODES * D;

  const int gblocks = (N_NODES + 31) / 32;   // 3125
  const int tiles = (N_NODES + 63) / 64;     // 1563

  // CSR build: no global atomics, no memset
  k_bcount<<<EB, 256, 0, stream>>>(ei, relbase);
  k_scan_bkt<<<NBKT, 256, 0, stream>>>(relbase, bktsum);
  k_scan_start<<<1, 512, 0, stream>>>(bktsum, bktstart);
  k_group<<<EB, 256, 0, stream>>>(ei, relbase, bktstart, grouped);
  k_build<<<NBKT, 256, 0, stream>>>(grouped, bktstart, bktsum, deg, cursor, ssrc);

  k_cvt<<<(N_NODES * D / 4 + 255) / 256, 256, 0, stream>>>(x, xb);

  // layer 1: gather bf16 xb -> bf16 aggb1; MFMA gemm(aggb1, xb) -> bf16 h1
  k_gather<false><<<gblocks, 256, 0, stream>>>(cursor, deg, ssrc, xb, aggb1);
  k_gemm_mfma<false, true><<<tiles, 256, 0, stream>>>(
      aggb1, xb, w1_l, b1_l, w1_r, bn1_g, bn1_b, bn1_m, bn1_v, h1);

  // layer 2: gather bf16 h1 -> f32 agg in d_out; MFMA gemm in-place on d_out
  k_gather<true><<<gblocks, 256, 0, stream>>>(cursor, deg, ssrc, h1, d_out);
  k_gemm_mfma<true, false><<<tiles, 256, 0, stream>>>(
      d_out, h1, w2_l, b2_l, w2_r, bn2_g, bn2_b, bn2_m, bn2_v, d_out);
}

// Round 12
// 192.409 us; speedup vs baseline: 1.9466x; 1.0190x over previous
//
#include <hip/hip_runtime.h>
#include <hip/hip_bf16.h>
#include <hip/hip_fp8.h>

#define N_NODES 100000
#define N_EDGES 1600000
#define D 64
#define BN_EPS 1e-5f
#define NBKT 391   // buckets of 256 nodes: ceil(100000/256)
#define EPB 1024   // edges per block in pass A/B
#define EB 1563    // ceil(N_EDGES/EPB)

typedef unsigned short u16x8 __attribute__((ext_vector_type(8)));
typedef __bf16 bf16x8 __attribute__((ext_vector_type(8)));
typedef float f32x4 __attribute__((ext_vector_type(4)));

// ---------------- CSR build (round-11 proven, atomic-free at global) ----------------

__global__ __launch_bounds__(256) void k_bcount(const int* __restrict__ ei,
                                                int* __restrict__ relbase) {
  __shared__ int h[NBKT];
  const int tid = threadIdx.x;
  for (int i = tid; i < NBKT; i += 256) h[i] = 0;
  __syncthreads();
  int e = blockIdx.x * EPB + tid * 4;
  if (e < N_EDGES) {
    int4 d = *(const int4*)(ei + N_EDGES + e);
    atomicAdd(&h[d.x >> 8], 1);
    atomicAdd(&h[d.y >> 8], 1);
    atomicAdd(&h[d.z >> 8], 1);
    atomicAdd(&h[d.w >> 8], 1);
  }
  __syncthreads();
  for (int i = tid; i < NBKT; i += 256)
    relbase[i * EB + blockIdx.x] = h[i];  // bucket-major
}

__global__ __launch_bounds__(256) void k_scan_bkt(int* __restrict__ relbase,
                                                  int* __restrict__ bktsum) {
  __shared__ int sd[256];
  __shared__ int carry;
  const int i = blockIdx.x;
  const int tid = threadIdx.x;
  if (tid == 0) carry = 0;
  __syncthreads();
  int* p = relbase + i * EB;
  for (int c0 = 0; c0 < EB; c0 += 256) {
    int idx = c0 + tid;
    int v = (idx < EB) ? p[idx] : 0;
    sd[tid] = v;
    __syncthreads();
    for (int ofs = 1; ofs < 256; ofs <<= 1) {
      int t = (tid >= ofs) ? sd[tid - ofs] : 0;
      __syncthreads();
      sd[tid] += t;
      __syncthreads();
    }
    int excl = carry + sd[tid] - v;
    if (idx < EB) p[idx] = excl;
    __syncthreads();
    if (tid == 255) carry += sd[255];
    __syncthreads();
  }
  if (tid == 0) bktsum[i] = carry;
}

__global__ __launch_bounds__(512) void k_scan_start(const int* __restrict__ bktsum,
                                                    int* __restrict__ bktstart) {
  __shared__ int sd[512];
  const int tid = threadIdx.x;
  int v = (tid < NBKT) ? bktsum[tid] : 0;
  sd[tid] = v;
  __syncthreads();
  for (int ofs = 1; ofs < 512; ofs <<= 1) {
    int t = (tid >= ofs) ? sd[tid - ofs] : 0;
    __syncthreads();
    sd[tid] += t;
    __syncthreads();
  }
  if (tid < NBKT) bktstart[tid] = sd[tid] - v;
}

__global__ __launch_bounds__(256) void k_group(const int* __restrict__ ei,
                                               const int* __restrict__ relbase,
                                               const int* __restrict__ bktstart,
                                               int* __restrict__ grouped) {
  __shared__ int cur[NBKT];
  const int tid = threadIdx.x;
  const int b = blockIdx.x;
  for (int i = tid; i < NBKT; i += 256)
    cur[i] = bktstart[i] + relbase[i * EB + b];
  __syncthreads();
  int e = b * EPB + tid * 4;
  if (e < N_EDGES) {
    int4 s = *(const int4*)(ei + e);
    int4 d = *(const int4*)(ei + N_EDGES + e);
    int p;
    p = atomicAdd(&cur[d.x >> 8], 1); grouped[p] = s.x | ((d.x & 255) << 17);
    p = atomicAdd(&cur[d.y >> 8], 1); grouped[p] = s.y | ((d.y & 255) << 17);
    p = atomicAdd(&cur[d.z >> 8], 1); grouped[p] = s.z | ((d.z & 255) << 17);
    p = atomicAdd(&cur[d.w >> 8], 1); grouped[p] = s.w | ((d.w & 255) << 17);
  }
}

__global__ __launch_bounds__(256) void k_build(const int* __restrict__ grouped,
                                               const int* __restrict__ bktstart,
                                               const int* __restrict__ bktsum,
                                               int* __restrict__ deg,
                                               int* __restrict__ cursor,
                                               int* __restrict__ ssrc) {
  __shared__ int cnt[256];
  __shared__ int sloc[256];
  __shared__ int cur2[256];
  const int i = blockIdx.x;
  const int tid = threadIdx.x;
  const int gstart = bktstart[i];
  const int gnum = bktsum[i];
  cnt[tid] = 0;
  __syncthreads();
  for (int j = tid; j < gnum; j += 256)
    atomicAdd(&cnt[((unsigned)grouped[gstart + j]) >> 17], 1);
  __syncthreads();
  int v = cnt[tid];
  sloc[tid] = v;
  __syncthreads();
  for (int ofs = 1; ofs < 256; ofs <<= 1) {
    int t = (tid >= ofs) ? sloc[tid - ofs] : 0;
    __syncthreads();
    sloc[tid] += t;
    __syncthreads();
  }
  int excl = sloc[tid] - v;
  int node = i * 256 + tid;
  if (node < N_NODES) {
    deg[node] = v;
    cursor[node] = gstart + excl;
  }
  cur2[tid] = gstart + excl;
  __syncthreads();
  for (int j = tid; j < gnum; j += 256) {
    int g = grouped[gstart + j];
    int p = atomicAdd(&cur2[((unsigned)g) >> 17], 1);
    ssrc[p] = g & 0x1ffff;
  }
}

// ---------------- helpers ----------------

static __device__ inline unsigned short f2bf_bits(float v) {
  __hip_bfloat16 h = __float2bfloat16(v);
  return *reinterpret_cast<unsigned short*>(&h);
}

static __device__ inline void add_bf8(float* a, uint4 v) {
  unsigned int b;
  b = v.x << 16;         a[0] += *(float*)&b;
  b = v.x & 0xffff0000u; a[1] += *(float*)&b;
  b = v.y << 16;         a[2] += *(float*)&b;
  b = v.y & 0xffff0000u; a[3] += *(float*)&b;
  b = v.z << 16;         a[4] += *(float*)&b;
  b = v.z & 0xffff0000u; a[5] += *(float*)&b;
  b = v.w << 16;         a[6] += *(float*)&b;
  b = v.w & 0xffff0000u; a[7] += *(float*)&b;
}

// decode+accumulate 8 fp8 e4m3 (one uint2 = 8B) into f32 accumulators
static __device__ inline void add_fp8x8(float* a, uint2 v) {
  __hip_fp8_e4m3 t;
#pragma unroll
  for (int j = 0; j < 4; ++j) {
    t.__x = (__hip_fp8_storage_t)((v.x >> (8 * j)) & 0xff);
    a[j] += (float)t;
  }
#pragma unroll
  for (int j = 0; j < 4; ++j) {
    t.__x = (__hip_fp8_storage_t)((v.y >> (8 * j)) & 0xff);
    a[4 + j] += (float)t;
  }
}

// x f32 -> bf16 copy (root path) AND fp8 e4m3 copy (layer-1 gather table)
__global__ __launch_bounds__(256) void k_cvt2(const float* __restrict__ x,
                                              unsigned short* __restrict__ xb,
                                              unsigned char* __restrict__ x8) {
  long i = (long)(blockIdx.x * 256 + threadIdx.x) * 4;
  if (i >= (long)N_NODES * D) return;
  float4 v = *(const float4*)(x + i);
  ushort4 u;
  u.x = f2bf_bits(v.x); u.y = f2bf_bits(v.y);
  u.z = f2bf_bits(v.z); u.w = f2bf_bits(v.w);
  *(ushort4*)(xb + i) = u;
  uchar4 c;
  c.x = __hip_fp8_e4m3(v.x).__x;
  c.y = __hip_fp8_e4m3(v.y).__x;
  c.z = __hip_fp8_e4m3(v.z).__x;
  c.w = __hip_fp8_e4m3(v.w).__x;
  *(uchar4*)(x8 + i) = c;
}

// ---------------- pure gather kernels ----------------

// bf16 table variant (round-9 proven)
template <bool OUT_F32>
__global__ __launch_bounds__(256) void k_gather(
    const int* __restrict__ cursor, const int* __restrict__ deg_a,
    const int* __restrict__ ssrc,
    const unsigned short* __restrict__ gsrc,  // bf16 [N][D]
    void* __restrict__ aggout) {
  const int gid = blockIdx.x * 32 + (threadIdx.x >> 3);
  const int q8 = threadIdx.x & 7;
  if (gid >= N_NODES) return;
  float a[8] = {0.f, 0.f, 0.f, 0.f, 0.f, 0.f, 0.f, 0.f};
  int st = cursor[gid];
  int dg = deg_a[gid];
  int u = 0;
  for (; u + 8 <= dg; u += 8) {
    int s0 = ssrc[st + u + 0], s1 = ssrc[st + u + 1];
    int s2 = ssrc[st + u + 2], s3 = ssrc[st + u + 3];
    int s4 = ssrc[st + u + 4], s5 = ssrc[st + u + 5];
    int s6 = ssrc[st + u + 6], s7 = ssrc[st + u + 7];
    uint4 v0 = *((const uint4*)(gsrc + (long)s0 * D) + q8);
    uint4 v1 = *((const uint4*)(gsrc + (long)s1 * D) + q8);
    uint4 v2 = *((const uint4*)(gsrc + (long)s2 * D) + q8);
    uint4 v3 = *((const uint4*)(gsrc + (long)s3 * D) + q8);
    uint4 v4 = *((const uint4*)(gsrc + (long)s4 * D) + q8);
    uint4 v5 = *((const uint4*)(gsrc + (long)s5 * D) + q8);
    uint4 v6 = *((const uint4*)(gsrc + (long)s6 * D) + q8);
    uint4 v7 = *((const uint4*)(gsrc + (long)s7 * D) + q8);
    add_bf8(a, v0); add_bf8(a, v1); add_bf8(a, v2); add_bf8(a, v3);
    add_bf8(a, v4); add_bf8(a, v5); add_bf8(a, v6); add_bf8(a, v7);
  }
  if (u + 4 <= dg) {
    int s0 = ssrc[st + u + 0], s1 = ssrc[st + u + 1];
    int s2 = ssrc[st + u + 2], s3 = ssrc[st + u + 3];
    uint4 v0 = *((const uint4*)(gsrc + (long)s0 * D) + q8);
    uint4 v1 = *((const uint4*)(gsrc + (long)s1 * D) + q8);
    uint4 v2 = *((const uint4*)(gsrc + (long)s2 * D) + q8);
    uint4 v3 = *((const uint4*)(gsrc + (long)s3 * D) + q8);
    add_bf8(a, v0); add_bf8(a, v1); add_bf8(a, v2); add_bf8(a, v3);
    u += 4;
  }
  for (; u < dg; ++u) {
    uint4 v = *((const uint4*)(gsrc + (long)ssrc[st + u] * D) + q8);
    add_bf8(a, v);
  }
  float invd = 1.0f / fmaxf((float)dg, 1.0f);
#pragma unroll
  for (int j = 0; j < 8; ++j) a[j] *= invd;
  if constexpr (OUT_F32) {
    float* p = (float*)aggout + (long)gid * D + q8 * 8;
    *(float4*)(p + 0) = make_float4(a[0], a[1], a[2], a[3]);
    *(float4*)(p + 4) = make_float4(a[4], a[5], a[6], a[7]);
  } else {
    ushort4 u0, u1;
    u0.x = f2bf_bits(a[0]); u0.y = f2bf_bits(a[1]);
    u0.z = f2bf_bits(a[2]); u0.w = f2bf_bits(a[3]);
    u1.x = f2bf_bits(a[4]); u1.y = f2bf_bits(a[5]);
    u1.z = f2bf_bits(a[6]); u1.w = f2bf_bits(a[7]);
    unsigned short* p = (unsigned short*)aggout + (long)gid * D + q8 * 8;
    *(ushort4*)(p + 0) = u0;
    *(ushort4*)(p + 4) = u1;
  }
}

// fp8 table variant: rows are 64B (one cache line), uint2 (8B) per lane.
__global__ __launch_bounds__(256) void k_gather_fp8(
    const int* __restrict__ cursor, const int* __restrict__ deg_a,
    const int* __restrict__ ssrc,
    const unsigned char* __restrict__ gsrc,  // fp8 [N][D]
    unsigned short* __restrict__ aggout) {   // bf16 agg
  const int gid = blockIdx.x * 32 + (threadIdx.x >> 3);
  const int q8 = threadIdx.x & 7;
  if (gid >= N_NODES) return;
  float a[8] = {0.f, 0.f, 0.f, 0.f, 0.f, 0.f, 0.f, 0.f};
  int st = cursor[gid];
  int dg = deg_a[gid];
  int u = 0;
  for (; u + 8 <= dg; u += 8) {
    int s0 = ssrc[st + u + 0], s1 = ssrc[st + u + 1];
    int s2 = ssrc[st + u + 2], s3 = ssrc[st + u + 3];
    int s4 = ssrc[st + u + 4], s5 = ssrc[st + u + 5];
    int s6 = ssrc[st + u + 6], s7 = ssrc[st + u + 7];
    uint2 v0 = *((const uint2*)(gsrc + (long)s0 * D) + q8);
    uint2 v1 = *((const uint2*)(gsrc + (long)s1 * D) + q8);
    uint2 v2 = *((const uint2*)(gsrc + (long)s2 * D) + q8);
    uint2 v3 = *((const uint2*)(gsrc + (long)s3 * D) + q8);
    uint2 v4 = *((const uint2*)(gsrc + (long)s4 * D) + q8);
    uint2 v5 = *((const uint2*)(gsrc + (long)s5 * D) + q8);
    uint2 v6 = *((const uint2*)(gsrc + (long)s6 * D) + q8);
    uint2 v7 = *((const uint2*)(gsrc + (long)s7 * D) + q8);
    add_fp8x8(a, v0); add_fp8x8(a, v1); add_fp8x8(a, v2); add_fp8x8(a, v3);
    add_fp8x8(a, v4); add_fp8x8(a, v5); add_fp8x8(a, v6); add_fp8x8(a, v7);
  }
  if (u + 4 <= dg) {
    int s0 = ssrc[st + u + 0], s1 = ssrc[st + u + 1];
    int s2 = ssrc[st + u + 2], s3 = ssrc[st + u + 3];
    uint2 v0 = *((const uint2*)(gsrc + (long)s0 * D) + q8);
    uint2 v1 = *((const uint2*)(gsrc + (long)s1 * D) + q8);
    uint2 v2 = *((const uint2*)(gsrc + (long)s2 * D) + q8);
    uint2 v3 = *((const uint2*)(gsrc + (long)s3 * D) + q8);
    add_fp8x8(a, v0); add_fp8x8(a, v1); add_fp8x8(a, v2); add_fp8x8(a, v3);
    u += 4;
  }
  for (; u < dg; ++u) {
    uint2 v = *((const uint2*)(gsrc + (long)ssrc[st + u] * D) + q8);
    add_fp8x8(a, v);
  }
  float invd = 1.0f / fmaxf((float)dg, 1.0f);
#pragma unroll
  for (int j = 0; j < 8; ++j) a[j] *= invd;
  ushort4 u0, u1;
  u0.x = f2bf_bits(a[0]); u0.y = f2bf_bits(a[1]);
  u0.z = f2bf_bits(a[2]); u0.w = f2bf_bits(a[3]);
  u1.x = f2bf_bits(a[4]); u1.y = f2bf_bits(a[5]);
  u1.z = f2bf_bits(a[6]); u1.w = f2bf_bits(a[7]);
  unsigned short* p = aggout + (long)gid * D + q8 * 8;
  *(ushort4*)(p + 0) = u0;
  *(ushort4*)(p + 4) = u1;
}

// ---------------- MFMA GEMM + ELU + BN (round-10 proven) ----------------

template <bool AGG_F32, bool OUT_BF16>
__global__ __launch_bounds__(256) void k_gemm_mfma(
    const void* __restrict__ aggp,             // [N][64] bf16 or f32
    const unsigned short* __restrict__ rootp,  // bf16 [N][64]
    const float* __restrict__ wl, const float* __restrict__ bl,
    const float* __restrict__ wr,
    const float* __restrict__ gamma, const float* __restrict__ beta,
    const float* __restrict__ mean, const float* __restrict__ var,
    void* __restrict__ out) {
  const int tid = threadIdx.x;
  const int lane = tid & 63;
  const int wv = tid >> 6;
  const int c16 = lane & 15;
  const int kg = lane >> 4;
  const int node0 = blockIdx.x * 64 + wv * 16;

  bf16x8 bfr[4][4];
#pragma unroll
  for (int kt = 0; kt < 4; ++kt) {
    const float* wsrc = (kt < 2) ? wl : wr;
    const int kofs = (kt & 1) * 32 + kg * 8;
#pragma unroll
    for (int ot = 0; ot < 4; ++ot) {
      const float* p = wsrc + (long)(ot * 16 + c16) * 64 + kofs;
      float4 f0 = *(const float4*)p;
      float4 f1 = *(const float4*)(p + 4);
      u16x8 u;
      u[0] = f2bf_bits(f0.x); u[1] = f2bf_bits(f0.y);
      u[2] = f2bf_bits(f0.z); u[3] = f2bf_bits(f0.w);
      u[4] = f2bf_bits(f1.x); u[5] = f2bf_bits(f1.y);
      u[6] = f2bf_bits(f1.z); u[7] = f2bf_bits(f1.w);
      bfr[kt][ot] = __builtin_bit_cast(bf16x8, u);
    }
  }

  long nrow = node0 + c16;
  long nclamp = (nrow < N_NODES) ? nrow : (N_NODES - 1);
  bf16x8 afr[4];
  if constexpr (AGG_F32) {
    const float* ap = (const float*)aggp + nclamp * D;
#pragma unroll
    for (int kt = 0; kt < 2; ++kt) {
      float4 f0 = *(const float4*)(ap + kt * 32 + kg * 8);
      float4 f1 = *(const float4*)(ap + kt * 32 + kg * 8 + 4);
      u16x8 u;
      u[0] = f2bf_bits(f0.x); u[1] = f2bf_bits(f0.y);
      u[2] = f2bf_bits(f0.z); u[3] = f2bf_bits(f0.w);
      u[4] = f2bf_bits(f1.x); u[5] = f2bf_bits(f1.y);
      u[6] = f2bf_bits(f1.z); u[7] = f2bf_bits(f1.w);
      afr[kt] = __builtin_bit_cast(bf16x8, u);
    }
  } else {
    const unsigned short* ap = (const unsigned short*)aggp + nclamp * D;
    afr[0] = __builtin_bit_cast(bf16x8, *(const u16x8*)(ap + kg * 8));
    afr[1] = __builtin_bit_cast(bf16x8, *(const u16x8*)(ap + 32 + kg * 8));
  }
  {
    const unsigned short* rp = rootp + nclamp * D;
    afr[2] = __builtin_bit_cast(bf16x8, *(const u16x8*)(rp + kg * 8));
    afr[3] = __builtin_bit_cast(bf16x8, *(const u16x8*)(rp + 32 + kg * 8));
  }

  f32x4 acc[4];
#pragma unroll
  for (int ot = 0; ot < 4; ++ot) acc[ot] = (f32x4){0.f, 0.f, 0.f, 0.f};
#pragma unroll
  for (int ot = 0; ot < 4; ++ot)
#pragma unroll
    for (int kt = 0; kt < 4; ++kt)
      acc[ot] = __builtin_amdgcn_mfma_f32_16x16x32_bf16(afr[kt], bfr[kt][ot],
                                                        acc[ot], 0, 0, 0);

  float scv[4], shv[4], blv[4];
#pragma unroll
  for (int ot = 0; ot < 4; ++ot) {
    int ch = ot * 16 + c16;
    float sc = gamma[ch] * rsqrtf(var[ch] + BN_EPS);
    scv[ot] = sc;
    shv[ot] = beta[ch] - mean[ch] * sc;
    blv[ot] = bl[ch];
  }
#pragma unroll
  for (int r = 0; r < 4; ++r) {
    long node_out = node0 + kg * 4 + r;
    if (node_out < N_NODES) {
#pragma unroll
      for (int ot = 0; ot < 4; ++ot) {
        float v = acc[ot][r] + blv[ot];
        v = v > 0.f ? v : expm1f(v);
        v = v * scv[ot] + shv[ot];
        if constexpr (OUT_BF16) {
          ((unsigned short*)out)[node_out * D + ot * 16 + c16] = f2bf_bits(v);
        } else {
          ((float*)out)[node_out * D + ot * 16 + c16] = v;
        }
      }
    }
  }
}

// ---------------- launch ----------------

extern "C" void kernel_launch(void* const* d_in, const int* in_sizes, int n_in,
                              void* d_out, int out_size, void* d_ws, size_t ws_size,
                              hipStream_t stream) {
  const float* x     = (const float*)d_in[0];
  const int*   ei    = (const int*)d_in[1];
  const float* w1_l  = (const float*)d_in[2];
  const float* b1_l  = (const float*)d_in[3];
  const float* w1_r  = (const float*)d_in[4];
  const float* w2_l  = (const float*)d_in[5];
  const float* b2_l  = (const float*)d_in[6];
  const float* w2_r  = (const float*)d_in[7];
  const float* bn1_g = (const float*)d_in[8];
  const float* bn1_b = (const float*)d_in[9];
  const float* bn1_m = (const float*)d_in[10];
  const float* bn1_v = (const float*)d_in[11];
  const float* bn2_g = (const float*)d_in[12];
  const float* bn2_b = (const float*)d_in[13];
  const float* bn2_m = (const float*)d_in[14];
  const float* bn2_v = (const float*)d_in[15];

  // ws layout (~20.0 MB):
  int* deg      = (int*)d_ws;            // [100096]
  int* cursor   = deg + 100096;          // [100096]
  int* bktsum   = cursor + 100096;       // [512]
  int* bktstart = bktsum + 512;          // [512]
  int* ssrc     = bktstart + 512;        // [E]
  unsigned short* h1 = (unsigned short*)(ssrc + N_EDGES);  // bf16 [N*D], 12.8 MB
  // aliases of the h1 region (all dead before h1 is written by gemm1):
  int* grouped  = (int*)h1;              // [E] 6.4 MB  (dead after k_build)
  int* relbase  = grouped + N_EDGES;     // [NBKT*EB] 2.44 MB (dead after k_group)
  unsigned char* x8 = (unsigned char*)h1;  // fp8 [N*D] 6.4 MB (written AFTER k_build,
                                           //  consumed by gather1, then gemm1 overwrites)

  // d_out reuse (round-9/10 proven): aggb1 = lower half, xb = upper half;
  // L2 gather overwrites all of d_out with f32 agg; L2 gemm in-place.
  unsigned short* aggb1 = (unsigned short*)d_out;
  unsigned short* xb    = (unsigned short*)d_out + (size_t)N_NODES * D;

  const int gblocks = (N_NODES + 31) / 32;   // 3125
  const int tiles = (N_NODES + 63) / 64;     // 1563

  // CSR build: no global atomics, no memset
  k_bcount<<<EB, 256, 0, stream>>>(ei, relbase);
  k_scan_bkt<<<NBKT, 256, 0, stream>>>(relbase, bktsum);
  k_scan_start<<<1, 512, 0, stream>>>(bktsum, bktstart);
  k_group<<<EB, 256, 0, stream>>>(ei, relbase, bktstart, grouped);
  k_build<<<NBKT, 256, 0, stream>>>(grouped, bktstart, bktsum, deg, cursor, ssrc);

  // x -> bf16 xb (root path) + fp8 x8 (gather table); after k_build (aliasing)
  k_cvt2<<<(N_NODES * D / 4 + 255) / 256, 256, 0, stream>>>(x, xb, x8);

  // layer 1: fp8 gather x8 -> bf16 aggb1; MFMA gemm(aggb1, xb) -> bf16 h1
  k_gather_fp8<<<gblocks, 256, 0, stream>>>(cursor, deg, ssrc, x8, aggb1);
  k_gemm_mfma<false, true><<<tiles, 256, 0, stream>>>(
      aggb1, xb, w1_l, b1_l, w1_r, bn1_g, bn1_b, bn1_m, bn1_v, h1);

  // layer 2: bf16 gather h1 -> f32 agg in d_out; MFMA gemm in-place on d_out
  k_gather<true><<<gblocks, 256, 0, stream>>>(cursor, deg, ssrc, h1, d_out);
  k_gemm_mfma<true, false><<<tiles, 256, 0, stream>>>(
      d_out, h1, w2_l, b2_l, w2_r, bn2_g, bn2_b, bn2_m, bn2_v, d_out);
}